// Round 1
// baseline (388.121 us; speedup 1.0000x reference)
//
#include <hip/hip_runtime.h>
#include <math.h>

// ---------------- problem constants ----------------
constexpr int NN1 = 65536;      // level-0 nodes
constexpr int EE  = 1048576;    // edges
constexpr int GG  = 64;         // graphs
constexpr int HH  = 128;        // hidden
constexpr int K1  = 512;        // keep after pool1 (per graph)
constexpr int M1  = GG * K1;    // 32768
constexpr int K2  = 256;        // keep after pool2
constexpr int M2  = GG * K2;    // 16384

// ---------------- GEMM: C[M,128] = A[M,128] @ W[128,128], fp32 ----------------
// 256 threads, 128 rows/block (2 rows/thread), 32 cols/thread.
// W staged in LDS with row stride 144 floats; col-group g at offset 36*g
// -> ds_read_b128 banks {0-3},{4-7},{8-11},{12-15}: conflict-free.
__global__ __launch_bounds__(256) void gemm_f32_128(const float* __restrict__ A,
                                                    const float* __restrict__ W,
                                                    float* __restrict__ C)
{
    __shared__ float Wl[128 * 144];   // 73728 B
    const int t = threadIdx.x;
#pragma unroll
    for (int i = 0; i < 16; ++i) {
        int idx = t + (i << 8);            // float4 index into W
        int k   = idx >> 5;                // row
        int c4  = (idx & 31) << 2;         // col (multiple of 4)
        float4 v = ((const float4*)W)[idx];
        *(float4*)&Wl[k * 144 + c4 + ((c4 >> 5) << 2)] = v;
    }
    __syncthreads();

    const int r0    = (blockIdx.x << 7) + (t >> 2);
    const int cg    = t & 3;
    const int cbase = cg * 36;             // swizzled base in LDS row
    const int c0    = cg << 5;             // logical col base

    float acc[2][32];
#pragma unroll
    for (int r = 0; r < 2; ++r)
#pragma unroll
        for (int j = 0; j < 32; ++j) acc[r][j] = 0.f;

    const float* A0 = A + ((size_t)r0 << 7);
#pragma unroll 1
    for (int k0 = 0; k0 < 128; k0 += 4) {
        float xv[2][4];
#pragma unroll
        for (int r = 0; r < 2; ++r)
            *(float4*)xv[r] = *(const float4*)(A0 + (size_t)(r << 6) * 128 + k0);
#pragma unroll
        for (int kk = 0; kk < 4; ++kk) {
            const float* wr = &Wl[(k0 + kk) * 144 + cbase];
            float wv[32];
#pragma unroll
            for (int j = 0; j < 32; j += 4) *(float4*)&wv[j] = *(const float4*)(wr + j);
#pragma unroll
            for (int r = 0; r < 2; ++r) {
                float xk = xv[r][kk];
#pragma unroll
                for (int j = 0; j < 32; ++j) acc[r][j] = fmaf(xk, wv[j], acc[r][j]);
            }
        }
    }
#pragma unroll
    for (int r = 0; r < 2; ++r) {
        float* cp = C + ((size_t)(r0 + (r << 6)) << 7) + c0;
#pragma unroll
        for (int j = 0; j < 32; j += 4) *(float4*)(cp + j) = *(const float4*)&acc[r][j];
    }
}

// ---------------- CSR build ----------------
__global__ void count1_k(const int* __restrict__ dst, int* __restrict__ cnt)
{
    int e = blockIdx.x * 256 + threadIdx.x;
    if (e >= EE) return;
    atomicAdd(&cnt[dst[e]], 1);
}

__global__ __launch_bounds__(256) void scan_block_k(int* __restrict__ data, int* __restrict__ bsum)
{
    __shared__ int lds[256];
    int t = threadIdx.x;
    int base = blockIdx.x * 1024;
    int4 v = *(const int4*)(data + base + t * 4);
    int s0 = v.x, s1 = s0 + v.y, s2 = s1 + v.z, s3 = s2 + v.w;
    lds[t] = s3;
    __syncthreads();
    int val = s3;
    for (int off = 1; off < 256; off <<= 1) {
        int u = (t >= off) ? lds[t - off] : 0;
        __syncthreads();
        val += u; lds[t] = val;
        __syncthreads();
    }
    int excl = val - s3;
    int4 o; o.x = excl + s0; o.y = excl + s1; o.z = excl + s2; o.w = excl + s3;
    *(int4*)(data + base + t * 4) = o;
    if (t == 255) bsum[blockIdx.x] = val;
}

__global__ void scan_mid_k(int* __restrict__ bsum, int nb)
{
    __shared__ int lds[64];
    int t = threadIdx.x;
    int v = (t < nb) ? bsum[t] : 0;
    lds[t] = v;
    __syncthreads();
    int val = v;
    for (int off = 1; off < 64; off <<= 1) {
        int u = (t >= off) ? lds[t - off] : 0;
        __syncthreads();
        val += u; lds[t] = val;
        __syncthreads();
    }
    if (t < nb) bsum[t] = val - v;   // exclusive
}

__global__ __launch_bounds__(256) void scan_add_k(const int* __restrict__ inc, const int* __restrict__ bsum,
                                                  int* __restrict__ rowptr, int* __restrict__ cur)
{
    int t = threadIdx.x;
    int base = blockIdx.x * 1024;
    int off = bsum[blockIdx.x];
    int4 v = *(const int4*)(inc + base + t * 4);
    int idx = base + t * 4;
    rowptr[idx + 1] = v.x + off; rowptr[idx + 2] = v.y + off;
    rowptr[idx + 3] = v.z + off; rowptr[idx + 4] = v.w + off;
    cur[idx + 1] = v.x + off; cur[idx + 2] = v.y + off;
    cur[idx + 3] = v.z + off; cur[idx + 4] = v.w + off;
    if (blockIdx.x == 0 && t == 0) { rowptr[0] = 0; cur[0] = 0; }
}

__global__ void fill1_k(const int* __restrict__ src, const int* __restrict__ dst,
                        int* __restrict__ cur, int* __restrict__ csr)
{
    int e = blockIdx.x * 256 + threadIdx.x;
    if (e >= EE) return;
    int pos = atomicAdd(&cur[dst[e]], 1);
    csr[pos] = src[e];
}

__global__ void dinv_k(const int* __restrict__ rowptr, float* __restrict__ dinv, int n)
{
    int i = blockIdx.x * 256 + threadIdx.x;
    if (i >= n) return;
    float deg = (float)(rowptr[i + 1] - rowptr[i]) + 1.0f;   // + self loop
    dinv[i] = 1.0f / sqrtf(deg);
}

// ---------------- GCN aggregation (+bias+relu) fused with score projection ----------------
// wave per node, 2 features per lane; hs[node] = dot(h_row, Ws) via shuffle reduce.
__global__ __launch_bounds__(256) void agg_feat_k(const float* __restrict__ XW,
                                                  const int* __restrict__ rowptr, const int* __restrict__ csr,
                                                  const float* __restrict__ dinv, const float* __restrict__ bias,
                                                  const float* __restrict__ Ws,
                                                  float* __restrict__ hout, float* __restrict__ hs, int n)
{
    int wid = threadIdx.x >> 6;
    int lane = threadIdx.x & 63;
    int node = (blockIdx.x << 2) + wid;
    if (node >= n) return;
    int f = lane << 1;
    float a0 = 0.f, a1 = 0.f;
    int p0 = rowptr[node], p1 = rowptr[node + 1];
    for (int p = p0; p < p1; ++p) {
        int s = csr[p];
        float ds = dinv[s];
        float2 v = *(const float2*)(XW + ((size_t)s << 7) + f);
        a0 = fmaf(ds, v.x, a0); a1 = fmaf(ds, v.y, a1);
    }
    float dd = dinv[node];
    float2 sv = *(const float2*)(XW + ((size_t)node << 7) + f);
    a0 = fmaf(dd, sv.x, a0); a1 = fmaf(dd, sv.y, a1);
    a0 = fmaf(a0, dd, bias[f]);     a1 = fmaf(a1, dd, bias[f + 1]);
    a0 = fmaxf(a0, 0.f);            a1 = fmaxf(a1, 0.f);
    *(float2*)(hout + ((size_t)node << 7) + f) = make_float2(a0, a1);
    float pq = fmaf(a0, Ws[f], a1 * Ws[f + 1]);
    for (int off = 32; off > 0; off >>= 1) pq += __shfl_down(pq, off, 64);
    if (lane == 0) hs[node] = pq;
}

// scalar score GCN: score[d] = dinv_d*(sum_in dinv_s*hs[s] + dinv_d*hs[d]) + bs
__global__ void score_k(const int* __restrict__ rowptr, const int* __restrict__ csr,
                        const float* __restrict__ dinv, const float* __restrict__ hs,
                        const float* __restrict__ bsp, float* __restrict__ score, int n)
{
    int i = blockIdx.x * 256 + threadIdx.x;
    if (i >= n) return;
    float acc = 0.f;
    int p0 = rowptr[i], p1 = rowptr[i + 1];
    for (int p = p0; p < p1; ++p) { int s = csr[p]; acc = fmaf(dinv[s], hs[s], acc); }
    float dd = dinv[i];
    acc = fmaf(dd, hs[i], acc);
    score[i] = fmaf(acc, dd, bsp[0]);
}

// ---------------- per-graph top-k via bitonic sort (ties: lower index first) ----------------
template <int NNE, int KK>
__global__ void topk_k(const float* __restrict__ score, int* __restrict__ perm)
{
    __shared__ unsigned long long keys[NNE];
    int t = threadIdx.x;
    int g = blockIdx.x;
    float s = score[g * NNE + t];
    unsigned u = __float_as_uint(s);
    u = (u & 0x80000000u) ? ~u : (u | 0x80000000u);           // monotone map
    keys[t] = (((unsigned long long)u) << 32) | (unsigned)(NNE - 1 - t);
    __syncthreads();
    for (int k = 2; k <= NNE; k <<= 1) {
        for (int j = k >> 1; j > 0; j >>= 1) {
            int ixj = t ^ j;
            if (ixj > t) {
                unsigned long long a = keys[t], b = keys[ixj];
                bool up = ((t & k) == 0);
                if ((a > b) == up) { keys[t] = b; keys[ixj] = a; }
            }
            __syncthreads();
        }
    }
    if (t < KK) {
        int idx = NNE - 1 - (int)(keys[NNE - 1 - t] & 0xFFFFFFFFu);
        perm[g * KK + t] = g * NNE + idx;     // global old id, rank order
    }
}

__global__ void mark_k(const int* __restrict__ perm, int* __restrict__ kept, int* __restrict__ nmap, int m)
{
    int i = blockIdx.x * 256 + threadIdx.x;
    if (i >= m) return;
    int o = perm[i];
    kept[o] = 1;
    nmap[o] = i;
}

__global__ void gather_k(const float* __restrict__ h, const float* __restrict__ score,
                         const int* __restrict__ perm, float* __restrict__ xn, int m)
{
    int gid = blockIdx.x * 256 + threadIdx.x;
    int node = gid >> 5, f4 = (gid & 31) << 2;
    if (node >= m) return;
    int o = perm[node];
    float tv = tanhf(score[o]);
    float4 v = *(const float4*)(h + ((size_t)o << 7) + f4);
    v.x *= tv; v.y *= tv; v.z *= tv; v.w *= tv;
    *(float4*)(xn + ((size_t)node << 7) + f4) = v;
}

template <int KN>
__global__ __launch_bounds__(128) void readout_k(const float* __restrict__ xn, float* __restrict__ xo)
{
    int g = blockIdx.x, t = threadIdx.x;
    const float* bp = xn + (size_t)g * KN * HH;
    float mx = -INFINITY, sm = 0.f;
    for (int r = 0; r < KN; ++r) {
        float v = bp[(size_t)r * HH + t];
        mx = fmaxf(mx, v);
        sm += v;
    }
    xo[g * 256 + t] = mx;
    xo[g * 256 + 128 + t] = sm * (1.0f / (float)KN);
}

// level-2 CSR over surviving edges (kept[src] & kept[dst]); ids remapped via nmap
__global__ void count2_k(const int* __restrict__ src, const int* __restrict__ dst,
                         const int* __restrict__ kept, const int* __restrict__ nmap, int* __restrict__ cnt)
{
    int e = blockIdx.x * 256 + threadIdx.x;
    if (e >= EE) return;
    int s = src[e], d = dst[e];
    if (kept[s] && kept[d]) atomicAdd(&cnt[nmap[d]], 1);
}

__global__ void fill2_k(const int* __restrict__ src, const int* __restrict__ dst,
                        const int* __restrict__ kept, const int* __restrict__ nmap,
                        int* __restrict__ cur, int* __restrict__ csr)
{
    int e = blockIdx.x * 256 + threadIdx.x;
    if (e >= EE) return;
    int s = src[e], d = dst[e];
    if (kept[s] && kept[d]) {
        int pos = atomicAdd(&cur[nmap[d]], 1);
        csr[pos] = nmap[s];
    }
}

// ---------------- head: z=x1+x2; relu(z@Wl1+bl1); @Wl2+bl2 ----------------
__global__ __launch_bounds__(128) void mlp_k(const float* __restrict__ x1, const float* __restrict__ x2,
                                             const float* __restrict__ Wl1, const float* __restrict__ bl1,
                                             const float* __restrict__ Wl2, const float* __restrict__ bl2,
                                             float* __restrict__ out)
{
    __shared__ float z[256];
    __shared__ float red[128];
    int g = blockIdx.x, t = threadIdx.x;
    z[t]       = x1[g * 256 + t]       + x2[g * 256 + t];
    z[t + 128] = x1[g * 256 + 128 + t] + x2[g * 256 + 128 + t];
    __syncthreads();
    float acc = bl1[t];
    for (int k = 0; k < 256; ++k) acc = fmaf(z[k], Wl1[k * 128 + t], acc);
    float zz = fmaxf(acc, 0.f);
    red[t] = zz * Wl2[t];
    __syncthreads();
    for (int off = 64; off > 0; off >>= 1) {
        if (t < off) red[t] += red[t + off];
        __syncthreads();
    }
    if (t == 0) out[g] = red[0] + bl2[0];
}

// ---------------- launch ----------------
extern "C" void kernel_launch(void* const* d_in, const int* in_sizes, int n_in,
                              void* d_out, int out_size, void* d_ws, size_t ws_size,
                              hipStream_t stream)
{
    const float* x   = (const float*)d_in[0];
    const int*   src = (const int*)d_in[1];
    const int*   dst = (const int*)d_in[2];
    const float* W1  = (const float*)d_in[3];
    const float* b1  = (const float*)d_in[4];
    const float* Ws1 = (const float*)d_in[5];
    const float* bs1 = (const float*)d_in[6];
    const float* W2  = (const float*)d_in[7];
    const float* b2  = (const float*)d_in[8];
    const float* Ws2 = (const float*)d_in[9];
    const float* bs2 = (const float*)d_in[10];
    const float* Wl1 = (const float*)d_in[11];
    const float* bl1 = (const float*)d_in[12];
    const float* Wl2 = (const float*)d_in[13];
    const float* bl2 = (const float*)d_in[14];
    float* out = (float*)d_out;
    char* ws = (char*)d_ws;

    // big regions (reused over time)
    float* XW1 = (float*)(ws);                        // 32MB [0,32M)
    float* h1  = (float*)(ws + ((size_t)32 << 20));   // 32MB [32M,64M)
    float* xn  = XW1;                                 // 16MB [0,16M)    (after agg1)
    float* XW2 = (float*)(ws + ((size_t)16 << 20));   // 16MB [16M,32M)  (after agg1)
    float* h2  = h1;                                  // 16MB [32M,48M)  (after gather1)
    float* xn2 = (float*)(ws + ((size_t)48 << 20));   // 8MB  [48M,56M)
    size_t SB = (size_t)64 << 20;
    auto alloc = [&](size_t bytes) { char* p = ws + SB; SB += (bytes + 255) & ~(size_t)255; return p; };
    float* hs1    = (float*)alloc(NN1 * 4);
    float* score1 = (float*)alloc(NN1 * 4);
    float* dinv1  = (float*)alloc(NN1 * 4);
    int* rowptr1  = (int*)alloc((NN1 + 1) * 4);
    int* cur1     = (int*)alloc((NN1 + 1) * 4);
    int* cnt1     = (int*)alloc(NN1 * 4);
    int* kept     = (int*)alloc(NN1 * 4);
    int* nmap     = (int*)alloc(NN1 * 4);
    int* csr1     = (int*)alloc((size_t)EE * 4);
    int* perm1    = (int*)alloc(M1 * 4);
    float* hs2    = (float*)alloc(M1 * 4);
    float* score2 = (float*)alloc(M1 * 4);
    float* dinv2  = (float*)alloc(M1 * 4);
    int* rowptr2  = (int*)alloc((M1 + 1) * 4);
    int* cur2     = (int*)alloc((M1 + 1) * 4);
    int* cnt2     = (int*)alloc(M1 * 4);
    int* csr2     = (int*)alloc((size_t)EE * 4);
    int* perm2    = (int*)alloc(M2 * 4);
    float* x1     = (float*)alloc(GG * 256 * 4);
    float* x2     = (float*)alloc(GG * 256 * 4);
    int* bsum     = (int*)alloc(64 * 4);
    (void)ws_size; (void)in_sizes; (void)n_in; (void)out_size;

    // ---- level 1: conv ----
    gemm_f32_128<<<NN1 / 128, 256, 0, stream>>>(x, W1, XW1);
    hipMemsetAsync(cnt1, 0, NN1 * 4, stream);
    count1_k<<<EE / 256, 256, 0, stream>>>(dst, cnt1);
    scan_block_k<<<NN1 / 1024, 256, 0, stream>>>(cnt1, bsum);
    scan_mid_k<<<1, 64, 0, stream>>>(bsum, NN1 / 1024);
    scan_add_k<<<NN1 / 1024, 256, 0, stream>>>(cnt1, bsum, rowptr1, cur1);
    fill1_k<<<EE / 256, 256, 0, stream>>>(src, dst, cur1, csr1);
    dinv_k<<<NN1 / 256, 256, 0, stream>>>(rowptr1, dinv1, NN1);
    agg_feat_k<<<NN1 / 4, 256, 0, stream>>>(XW1, rowptr1, csr1, dinv1, b1, Ws1, h1, hs1, NN1);
    // ---- pool 1 ----
    score_k<<<NN1 / 256, 256, 0, stream>>>(rowptr1, csr1, dinv1, hs1, bs1, score1, NN1);
    topk_k<1024, 512><<<GG, 1024, 0, stream>>>(score1, perm1);
    hipMemsetAsync(kept, 0, NN1 * 4, stream);
    mark_k<<<M1 / 256, 256, 0, stream>>>(perm1, kept, nmap, M1);
    gather_k<<<(M1 * 32) / 256, 256, 0, stream>>>(h1, score1, perm1, xn, M1);
    readout_k<K1><<<GG, 128, 0, stream>>>(xn, x1);
    // ---- level 2 CSR ----
    hipMemsetAsync(cnt2, 0, M1 * 4, stream);
    count2_k<<<EE / 256, 256, 0, stream>>>(src, dst, kept, nmap, cnt2);
    scan_block_k<<<M1 / 1024, 256, 0, stream>>>(cnt2, bsum);
    scan_mid_k<<<1, 64, 0, stream>>>(bsum, M1 / 1024);
    scan_add_k<<<M1 / 1024, 256, 0, stream>>>(cnt2, bsum, rowptr2, cur2);
    fill2_k<<<EE / 256, 256, 0, stream>>>(src, dst, kept, nmap, cur2, csr2);
    dinv_k<<<M1 / 256, 256, 0, stream>>>(rowptr2, dinv2, M1);
    // ---- level 2: conv ----
    gemm_f32_128<<<M1 / 128, 256, 0, stream>>>(xn, W2, XW2);
    agg_feat_k<<<M1 / 4, 256, 0, stream>>>(XW2, rowptr2, csr2, dinv2, b2, Ws2, h2, hs2, M1);
    // ---- pool 2 ----
    score_k<<<M1 / 256, 256, 0, stream>>>(rowptr2, csr2, dinv2, hs2, bs2, score2, M1);
    topk_k<512, 256><<<GG, 512, 0, stream>>>(score2, perm2);
    gather_k<<<(M2 * 32) / 256, 256, 0, stream>>>(h2, score2, perm2, xn2, M2);
    readout_k<K2><<<GG, 128, 0, stream>>>(xn2, x2);
    // ---- head ----
    mlp_k<<<GG, 128, 0, stream>>>(x1, x2, Wl1, bl1, Wl2, bl2, out);
}

// Round 2
// 332.051 us; speedup vs baseline: 1.1689x; 1.1689x over previous
//
#include <hip/hip_runtime.h>
#include <math.h>

// ---------------- problem constants ----------------
constexpr int NN1 = 65536;      // level-0 nodes
constexpr int EE  = 1048576;    // edges
constexpr int GG  = 64;         // graphs
constexpr int HH  = 128;        // hidden
constexpr int K1  = 512;        // keep after pool1 (per graph)
constexpr int M1  = GG * K1;    // 32768
constexpr int K2  = 256;        // keep after pool2
constexpr int M2  = GG * K2;    // 16384

// ---------------- GEMM: C[M,128] = A[M,128] @ W[128,128], fp32 ----------------
__global__ __launch_bounds__(256) void gemm_f32_128(const float* __restrict__ A,
                                                    const float* __restrict__ W,
                                                    float* __restrict__ C)
{
    __shared__ float Wl[128 * 144];   // 73728 B
    const int t = threadIdx.x;
#pragma unroll
    for (int i = 0; i < 16; ++i) {
        int idx = t + (i << 8);            // float4 index into W
        int k   = idx >> 5;                // row
        int c4  = (idx & 31) << 2;         // col (multiple of 4)
        float4 v = ((const float4*)W)[idx];
        *(float4*)&Wl[k * 144 + c4 + ((c4 >> 5) << 2)] = v;
    }
    __syncthreads();

    const int r0    = (blockIdx.x << 7) + (t >> 2);
    const int cg    = t & 3;
    const int cbase = cg * 36;             // swizzled base in LDS row
    const int c0    = cg << 5;             // logical col base

    float acc[2][32];
#pragma unroll
    for (int r = 0; r < 2; ++r)
#pragma unroll
        for (int j = 0; j < 32; ++j) acc[r][j] = 0.f;

    const float* A0 = A + ((size_t)r0 << 7);
#pragma unroll 1
    for (int k0 = 0; k0 < 128; k0 += 4) {
        float xv[2][4];
#pragma unroll
        for (int r = 0; r < 2; ++r)
            *(float4*)xv[r] = *(const float4*)(A0 + (size_t)(r << 6) * 128 + k0);
#pragma unroll
        for (int kk = 0; kk < 4; ++kk) {
            const float* wr = &Wl[(k0 + kk) * 144 + cbase];
            float wv[32];
#pragma unroll
            for (int j = 0; j < 32; j += 4) *(float4*)&wv[j] = *(const float4*)(wr + j);
#pragma unroll
            for (int r = 0; r < 2; ++r) {
                float xk = xv[r][kk];
#pragma unroll
                for (int j = 0; j < 32; ++j) acc[r][j] = fmaf(xk, wv[j], acc[r][j]);
            }
        }
    }
#pragma unroll
    for (int r = 0; r < 2; ++r) {
        float* cp = C + ((size_t)(r0 + (r << 6)) << 7) + c0;
#pragma unroll
        for (int j = 0; j < 32; j += 4) *(float4*)(cp + j) = *(const float4*)&acc[r][j];
    }
}

// ---------------- CSR build ----------------
__global__ void count1_k(const int* __restrict__ dst, int* __restrict__ cnt)
{
    int e = blockIdx.x * 256 + threadIdx.x;
    if (e >= EE) return;
    atomicAdd(&cnt[dst[e]], 1);
}

__global__ __launch_bounds__(256) void scan_block_k(int* __restrict__ data, int* __restrict__ bsum)
{
    __shared__ int lds[256];
    int t = threadIdx.x;
    int base = blockIdx.x * 1024;
    int4 v = *(const int4*)(data + base + t * 4);
    int s0 = v.x, s1 = s0 + v.y, s2 = s1 + v.z, s3 = s2 + v.w;
    lds[t] = s3;
    __syncthreads();
    int val = s3;
    for (int off = 1; off < 256; off <<= 1) {
        int u = (t >= off) ? lds[t - off] : 0;
        __syncthreads();
        val += u; lds[t] = val;
        __syncthreads();
    }
    int excl = val - s3;
    int4 o; o.x = excl + s0; o.y = excl + s1; o.z = excl + s2; o.w = excl + s3;
    *(int4*)(data + base + t * 4) = o;
    if (t == 255) bsum[blockIdx.x] = val;
}

__global__ void scan_mid_k(int* __restrict__ bsum, int nb)
{
    __shared__ int lds[64];
    int t = threadIdx.x;
    int v = (t < nb) ? bsum[t] : 0;
    lds[t] = v;
    __syncthreads();
    int val = v;
    for (int off = 1; off < 64; off <<= 1) {
        int u = (t >= off) ? lds[t - off] : 0;
        __syncthreads();
        val += u; lds[t] = val;
        __syncthreads();
    }
    if (t < nb) bsum[t] = val - v;   // exclusive
}

__global__ __launch_bounds__(256) void scan_add_k(const int* __restrict__ inc, const int* __restrict__ bsum,
                                                  int* __restrict__ rowptr, int* __restrict__ cur)
{
    int t = threadIdx.x;
    int base = blockIdx.x * 1024;
    int off = bsum[blockIdx.x];
    int4 v = *(const int4*)(inc + base + t * 4);
    int idx = base + t * 4;
    rowptr[idx + 1] = v.x + off; rowptr[idx + 2] = v.y + off;
    rowptr[idx + 3] = v.z + off; rowptr[idx + 4] = v.w + off;
    cur[idx + 1] = v.x + off; cur[idx + 2] = v.y + off;
    cur[idx + 3] = v.z + off; cur[idx + 4] = v.w + off;
    if (blockIdx.x == 0 && t == 0) { rowptr[0] = 0; cur[0] = 0; }
}

__global__ void fill1_k(const int* __restrict__ src, const int* __restrict__ dst,
                        int* __restrict__ cur, int* __restrict__ csr)
{
    int e = blockIdx.x * 256 + threadIdx.x;
    if (e >= EE) return;
    int pos = atomicAdd(&cur[dst[e]], 1);
    csr[pos] = src[e];
}

__global__ void dinv_k(const int* __restrict__ rowptr, float* __restrict__ dinv, int n)
{
    int i = blockIdx.x * 256 + threadIdx.x;
    if (i >= n) return;
    float deg = (float)(rowptr[i + 1] - rowptr[i]) + 1.0f;   // + self loop
    dinv[i] = 1.0f / sqrtf(deg);
}

// ---------------- GCN aggregation (+bias+relu) fused with score projection ----------------
// wave per node, 2 features per lane; 4-way unrolled neighbor loop for memory ILP.
__global__ __launch_bounds__(256) void agg_feat_k(const float* __restrict__ XW,
                                                  const int* __restrict__ rowptr, const int* __restrict__ csr,
                                                  const float* __restrict__ dinv, const float* __restrict__ bias,
                                                  const float* __restrict__ Ws,
                                                  float* __restrict__ hout, float* __restrict__ hs, int n)
{
    int wid = threadIdx.x >> 6;
    int lane = threadIdx.x & 63;
    int node = (blockIdx.x << 2) + wid;
    if (node >= n) return;
    int f = lane << 1;
    const float* XWf = XW + f;
    float a0 = 0.f, a1 = 0.f, b0 = 0.f, b1 = 0.f;
    float c0 = 0.f, c1 = 0.f, e0 = 0.f, e1 = 0.f;
    int p0 = rowptr[node], p1 = rowptr[node + 1];
    int p = p0;
    for (; p + 4 <= p1; p += 4) {
        int s0 = csr[p], s1 = csr[p + 1], s2 = csr[p + 2], s3 = csr[p + 3];
        float d0 = dinv[s0], d1 = dinv[s1], d2 = dinv[s2], d3 = dinv[s3];
        float2 v0 = *(const float2*)(XWf + ((size_t)s0 << 7));
        float2 v1 = *(const float2*)(XWf + ((size_t)s1 << 7));
        float2 v2 = *(const float2*)(XWf + ((size_t)s2 << 7));
        float2 v3 = *(const float2*)(XWf + ((size_t)s3 << 7));
        a0 = fmaf(d0, v0.x, a0); a1 = fmaf(d0, v0.y, a1);
        b0 = fmaf(d1, v1.x, b0); b1 = fmaf(d1, v1.y, b1);
        c0 = fmaf(d2, v2.x, c0); c1 = fmaf(d2, v2.y, c1);
        e0 = fmaf(d3, v3.x, e0); e1 = fmaf(d3, v3.y, e1);
    }
    for (; p < p1; ++p) {
        int s = csr[p];
        float ds = dinv[s];
        float2 v = *(const float2*)(XWf + ((size_t)s << 7));
        a0 = fmaf(ds, v.x, a0); a1 = fmaf(ds, v.y, a1);
    }
    a0 = (a0 + b0) + (c0 + e0);
    a1 = (a1 + b1) + (c1 + e1);
    float dd = dinv[node];
    float2 sv = *(const float2*)(XWf + ((size_t)node << 7));
    a0 = fmaf(dd, sv.x, a0); a1 = fmaf(dd, sv.y, a1);
    a0 = fmaf(a0, dd, bias[f]);     a1 = fmaf(a1, dd, bias[f + 1]);
    a0 = fmaxf(a0, 0.f);            a1 = fmaxf(a1, 0.f);
    *(float2*)(hout + ((size_t)node << 7) + f) = make_float2(a0, a1);
    float pq = fmaf(a0, Ws[f], a1 * Ws[f + 1]);
    for (int off = 32; off > 0; off >>= 1) pq += __shfl_down(pq, off, 64);
    if (lane == 0) hs[node] = pq;
}

// scalar score GCN: score[d] = dinv_d*(sum_in dinv_s*hs[s] + dinv_d*hs[d]) + bs
__global__ void score_k(const int* __restrict__ rowptr, const int* __restrict__ csr,
                        const float* __restrict__ dinv, const float* __restrict__ hs,
                        const float* __restrict__ bsp, float* __restrict__ score, int n)
{
    int i = blockIdx.x * 256 + threadIdx.x;
    if (i >= n) return;
    float a = 0.f, b = 0.f, c = 0.f, e = 0.f;
    int p0 = rowptr[i], p1 = rowptr[i + 1];
    int p = p0;
    for (; p + 4 <= p1; p += 4) {
        int s0 = csr[p], s1 = csr[p + 1], s2 = csr[p + 2], s3 = csr[p + 3];
        a = fmaf(dinv[s0], hs[s0], a);
        b = fmaf(dinv[s1], hs[s1], b);
        c = fmaf(dinv[s2], hs[s2], c);
        e = fmaf(dinv[s3], hs[s3], e);
    }
    for (; p < p1; ++p) { int s = csr[p]; a = fmaf(dinv[s], hs[s], a); }
    float acc = (a + b) + (c + e);
    float dd = dinv[i];
    acc = fmaf(dd, hs[i], acc);
    score[i] = fmaf(acc, dd, bsp[0]);
}

// ---------------- per-graph top-k via bitonic sort (ties: lower index first) ----------------
template <int NNE, int KK>
__global__ void topk_k(const float* __restrict__ score, int* __restrict__ perm)
{
    __shared__ unsigned long long keys[NNE];
    int t = threadIdx.x;
    int g = blockIdx.x;
    float s = score[g * NNE + t];
    unsigned u = __float_as_uint(s);
    u = (u & 0x80000000u) ? ~u : (u | 0x80000000u);           // monotone map
    keys[t] = (((unsigned long long)u) << 32) | (unsigned)(NNE - 1 - t);
    __syncthreads();
    for (int k = 2; k <= NNE; k <<= 1) {
        for (int j = k >> 1; j > 0; j >>= 1) {
            int ixj = t ^ j;
            if (ixj > t) {
                unsigned long long a = keys[t], b = keys[ixj];
                bool up = ((t & k) == 0);
                if ((a > b) == up) { keys[t] = b; keys[ixj] = a; }
            }
            __syncthreads();
        }
    }
    if (t < KK) {
        int idx = NNE - 1 - (int)(keys[NNE - 1 - t] & 0xFFFFFFFFu);
        perm[g * KK + t] = g * NNE + idx;     // global old id, rank order
    }
}

__global__ void mark_k(const int* __restrict__ perm, int* __restrict__ kept, int* __restrict__ nmap, int m)
{
    int i = blockIdx.x * 256 + threadIdx.x;
    if (i >= m) return;
    int o = perm[i];
    kept[o] = 1;
    nmap[o] = i;
}

__global__ void gather_k(const float* __restrict__ h, const float* __restrict__ score,
                         const int* __restrict__ perm, float* __restrict__ xn, int m)
{
    int gid = blockIdx.x * 256 + threadIdx.x;
    int node = gid >> 5, f4 = (gid & 31) << 2;
    if (node >= m) return;
    int o = perm[node];
    float tv = tanhf(score[o]);
    float4 v = *(const float4*)(h + ((size_t)o << 7) + f4);
    v.x *= tv; v.y *= tv; v.z *= tv; v.w *= tv;
    *(float4*)(xn + ((size_t)node << 7) + f4) = v;
}

template <int KN>
__global__ __launch_bounds__(128) void readout_k(const float* __restrict__ xn, float* __restrict__ xo)
{
    int g = blockIdx.x, t = threadIdx.x;
    const float* bp = xn + (size_t)g * KN * HH;
    float mx = -INFINITY, sm = 0.f;
    for (int r = 0; r < KN; ++r) {
        float v = bp[(size_t)r * HH + t];
        mx = fmaxf(mx, v);
        sm += v;
    }
    xo[g * 256 + t] = mx;
    xo[g * 256 + 128 + t] = sm * (1.0f / (float)KN);
}

// level-2 CSR over surviving edges (kept[src] & kept[dst]); ids remapped via nmap
__global__ void count2_k(const int* __restrict__ src, const int* __restrict__ dst,
                         const int* __restrict__ kept, const int* __restrict__ nmap, int* __restrict__ cnt)
{
    int e = blockIdx.x * 256 + threadIdx.x;
    if (e >= EE) return;
    int s = src[e], d = dst[e];
    if (kept[s] && kept[d]) atomicAdd(&cnt[nmap[d]], 1);
}

__global__ void fill2_k(const int* __restrict__ src, const int* __restrict__ dst,
                        const int* __restrict__ kept, const int* __restrict__ nmap,
                        int* __restrict__ cur, int* __restrict__ csr)
{
    int e = blockIdx.x * 256 + threadIdx.x;
    if (e >= EE) return;
    int s = src[e], d = dst[e];
    if (kept[s] && kept[d]) {
        int pos = atomicAdd(&cur[nmap[d]], 1);
        csr[pos] = nmap[s];
    }
}

// ---------------- head: z=x1+x2; relu(z@Wl1+bl1); @Wl2+bl2 ----------------
__global__ __launch_bounds__(128) void mlp_k(const float* __restrict__ x1, const float* __restrict__ x2,
                                             const float* __restrict__ Wl1, const float* __restrict__ bl1,
                                             const float* __restrict__ Wl2, const float* __restrict__ bl2,
                                             float* __restrict__ out)
{
    __shared__ float z[256];
    __shared__ float red[128];
    int g = blockIdx.x, t = threadIdx.x;
    z[t]       = x1[g * 256 + t]       + x2[g * 256 + t];
    z[t + 128] = x1[g * 256 + 128 + t] + x2[g * 256 + 128 + t];
    __syncthreads();
    float acc = bl1[t];
    for (int k = 0; k < 256; ++k) acc = fmaf(z[k], Wl1[k * 128 + t], acc);
    float zz = fmaxf(acc, 0.f);
    red[t] = zz * Wl2[t];
    __syncthreads();
    for (int off = 64; off > 0; off >>= 1) {
        if (t < off) red[t] += red[t + off];
        __syncthreads();
    }
    if (t == 0) out[g] = red[0] + bl2[0];
}

// ---------------- launch ----------------
extern "C" void kernel_launch(void* const* d_in, const int* in_sizes, int n_in,
                              void* d_out, int out_size, void* d_ws, size_t ws_size,
                              hipStream_t stream)
{
    const float* x   = (const float*)d_in[0];
    const int*   src = (const int*)d_in[1];
    const int*   dst = (const int*)d_in[2];
    const float* W1  = (const float*)d_in[3];
    const float* b1  = (const float*)d_in[4];
    const float* Ws1 = (const float*)d_in[5];
    const float* bs1 = (const float*)d_in[6];
    const float* W2  = (const float*)d_in[7];
    const float* b2  = (const float*)d_in[8];
    const float* Ws2 = (const float*)d_in[9];
    const float* bs2 = (const float*)d_in[10];
    const float* Wl1 = (const float*)d_in[11];
    const float* bl1 = (const float*)d_in[12];
    const float* Wl2 = (const float*)d_in[13];
    const float* bl2 = (const float*)d_in[14];
    float* out = (float*)d_out;
    char* ws = (char*)d_ws;

    // big regions (reused over time)
    float* XW1 = (float*)(ws);                        // 32MB [0,32M)
    float* h1  = (float*)(ws + ((size_t)32 << 20));   // 32MB [32M,64M)
    float* xn  = XW1;                                 // 16MB [0,16M)    (after agg1)
    float* XW2 = (float*)(ws + ((size_t)16 << 20));   // 16MB [16M,32M)  (after agg1)
    float* h2  = h1;                                  // 16MB [32M,48M)  (after gather1)
    float* xn2 = (float*)(ws + ((size_t)48 << 20));   // 8MB  [48M,56M)
    size_t SB = (size_t)64 << 20;
    auto alloc = [&](size_t bytes) { char* p = ws + SB; SB += (bytes + 255) & ~(size_t)255; return p; };
    float* hs1    = (float*)alloc(NN1 * 4);
    float* score1 = (float*)alloc(NN1 * 4);
    float* dinv1  = (float*)alloc(NN1 * 4);
    int* rowptr1  = (int*)alloc((NN1 + 1) * 4);
    int* cur1     = (int*)alloc((NN1 + 1) * 4);
    int* cnt1     = (int*)alloc(NN1 * 4);
    int* kept     = (int*)alloc(NN1 * 4);
    int* nmap     = (int*)alloc(NN1 * 4);
    int* csr1     = (int*)alloc((size_t)EE * 4);
    int* perm1    = (int*)alloc(M1 * 4);
    float* hs2    = (float*)alloc(M1 * 4);
    float* score2 = (float*)alloc(M1 * 4);
    float* dinv2  = (float*)alloc(M1 * 4);
    int* rowptr2  = (int*)alloc((M1 + 1) * 4);
    int* cur2     = (int*)alloc((M1 + 1) * 4);
    int* cnt2     = (int*)alloc(M1 * 4);
    int* csr2     = (int*)alloc((size_t)EE * 4);
    int* perm2    = (int*)alloc(M2 * 4);
    float* x1     = (float*)alloc(GG * 256 * 4);
    float* x2     = (float*)alloc(GG * 256 * 4);
    int* bsum     = (int*)alloc(64 * 4);
    (void)ws_size; (void)in_sizes; (void)n_in; (void)out_size;

    // ---- level 1: conv ----
    gemm_f32_128<<<NN1 / 128, 256, 0, stream>>>(x, W1, XW1);
    hipMemsetAsync(cnt1, 0, NN1 * 4, stream);
    count1_k<<<EE / 256, 256, 0, stream>>>(dst, cnt1);
    scan_block_k<<<NN1 / 1024, 256, 0, stream>>>(cnt1, bsum);
    scan_mid_k<<<1, 64, 0, stream>>>(bsum, NN1 / 1024);
    scan_add_k<<<NN1 / 1024, 256, 0, stream>>>(cnt1, bsum, rowptr1, cur1);
    fill1_k<<<EE / 256, 256, 0, stream>>>(src, dst, cur1, csr1);
    dinv_k<<<NN1 / 256, 256, 0, stream>>>(rowptr1, dinv1, NN1);
    agg_feat_k<<<NN1 / 4, 256, 0, stream>>>(XW1, rowptr1, csr1, dinv1, b1, Ws1, h1, hs1, NN1);
    // ---- pool 1 ----
    score_k<<<NN1 / 256, 256, 0, stream>>>(rowptr1, csr1, dinv1, hs1, bs1, score1, NN1);
    topk_k<1024, 512><<<GG, 1024, 0, stream>>>(score1, perm1);
    hipMemsetAsync(kept, 0, NN1 * 4, stream);
    mark_k<<<M1 / 256, 256, 0, stream>>>(perm1, kept, nmap, M1);
    gather_k<<<(M1 * 32) / 256, 256, 0, stream>>>(h1, score1, perm1, xn, M1);
    readout_k<K1><<<GG, 128, 0, stream>>>(xn, x1);
    // ---- level 2 CSR ----
    hipMemsetAsync(cnt2, 0, M1 * 4, stream);
    count2_k<<<EE / 256, 256, 0, stream>>>(src, dst, kept, nmap, cnt2);
    scan_block_k<<<M1 / 1024, 256, 0, stream>>>(cnt2, bsum);
    scan_mid_k<<<1, 64, 0, stream>>>(bsum, M1 / 1024);
    scan_add_k<<<M1 / 1024, 256, 0, stream>>>(cnt2, bsum, rowptr2, cur2);
    fill2_k<<<EE / 256, 256, 0, stream>>>(src, dst, kept, nmap, cur2, csr2);
    dinv_k<<<M1 / 256, 256, 0, stream>>>(rowptr2, dinv2, M1);
    // ---- level 2: conv ----
    gemm_f32_128<<<M1 / 128, 256, 0, stream>>>(xn, W2, XW2);
    agg_feat_k<<<M1 / 4, 256, 0, stream>>>(XW2, rowptr2, csr2, dinv2, b2, Ws2, h2, hs2, M1);
    // ---- pool 2 ----
    score_k<<<M1 / 256, 256, 0, stream>>>(rowptr2, csr2, dinv2, hs2, bs2, score2, M1);
    topk_k<512, 256><<<GG, 512, 0, stream>>>(score2, perm2);
    gather_k<<<(M2 * 32) / 256, 256, 0, stream>>>(h2, score2, perm2, xn2, M2);
    readout_k<K2><<<GG, 128, 0, stream>>>(xn2, x2);
    // ---- head ----
    mlp_k<<<GG, 128, 0, stream>>>(x1, x2, Wl1, bl1, Wl2, bl2, out);
}

// Round 3
// 301.975 us; speedup vs baseline: 1.2853x; 1.0996x over previous
//
#include <hip/hip_runtime.h>
#include <math.h>

// ---------------- problem constants ----------------
constexpr int NN1 = 65536;      // level-0 nodes
constexpr int EE  = 1048576;    // edges
constexpr int GG  = 64;         // graphs
constexpr int HH  = 128;        // hidden
constexpr int K1  = 512;        // keep after pool1 (per graph)
constexpr int M1  = GG * K1;    // 32768
constexpr int K2  = 256;        // keep after pool2
constexpr int M2  = GG * K2;    // 16384

__device__ __forceinline__ float4 f4add(float4 a, float4 b)
{
    a.x += b.x; a.y += b.y; a.z += b.z; a.w += b.w; return a;
}

// ---------------- GEMM: C[M,128] = dinv[r] * (A[M,128] @ W[128,128]), fp32 ----------------
__global__ __launch_bounds__(256) void gemm_f32_128(const float* __restrict__ A,
                                                    const float* __restrict__ W,
                                                    const float* __restrict__ dinv,
                                                    float* __restrict__ C)
{
    __shared__ float Wl[128 * 144];   // 73728 B
    const int t = threadIdx.x;
#pragma unroll
    for (int i = 0; i < 16; ++i) {
        int idx = t + (i << 8);            // float4 index into W
        int k   = idx >> 5;                // row
        int c4  = (idx & 31) << 2;         // col (multiple of 4)
        float4 v = ((const float4*)W)[idx];
        *(float4*)&Wl[k * 144 + c4 + ((c4 >> 5) << 2)] = v;
    }
    __syncthreads();

    const int r0    = (blockIdx.x << 7) + (t >> 2);
    const int cg    = t & 3;
    const int cbase = cg * 36;             // swizzled base in LDS row
    const int c0    = cg << 5;             // logical col base

    float acc[2][32];
#pragma unroll
    for (int r = 0; r < 2; ++r)
#pragma unroll
        for (int j = 0; j < 32; ++j) acc[r][j] = 0.f;

    const float* A0 = A + ((size_t)r0 << 7);
#pragma unroll 1
    for (int k0 = 0; k0 < 128; k0 += 4) {
        float xv[2][4];
#pragma unroll
        for (int r = 0; r < 2; ++r)
            *(float4*)xv[r] = *(const float4*)(A0 + (size_t)(r << 6) * 128 + k0);
#pragma unroll
        for (int kk = 0; kk < 4; ++kk) {
            const float* wr = &Wl[(k0 + kk) * 144 + cbase];
            float wv[32];
#pragma unroll
            for (int j = 0; j < 32; j += 4) *(float4*)&wv[j] = *(const float4*)(wr + j);
#pragma unroll
            for (int r = 0; r < 2; ++r) {
                float xk = xv[r][kk];
#pragma unroll
                for (int j = 0; j < 32; ++j) acc[r][j] = fmaf(xk, wv[j], acc[r][j]);
            }
        }
    }
#pragma unroll
    for (int r = 0; r < 2; ++r) {
        float sc = dinv[r0 + (r << 6)];
        float* cp = C + ((size_t)(r0 + (r << 6)) << 7) + c0;
#pragma unroll
        for (int j = 0; j < 32; j += 4) {
            float4 v = *(const float4*)&acc[r][j];
            v.x *= sc; v.y *= sc; v.z *= sc; v.w *= sc;
            *(float4*)(cp + j) = v;
        }
    }
}

// ---------------- CSR build ----------------
__global__ void count1_k(const int* __restrict__ dst, int* __restrict__ cnt)
{
    int e = blockIdx.x * 256 + threadIdx.x;
    if (e >= EE) return;
    atomicAdd(&cnt[dst[e]], 1);
}

__global__ __launch_bounds__(256) void scan_block_k(int* __restrict__ data, int* __restrict__ bsum)
{
    __shared__ int lds[256];
    int t = threadIdx.x;
    int base = blockIdx.x * 1024;
    int4 v = *(const int4*)(data + base + t * 4);
    int s0 = v.x, s1 = s0 + v.y, s2 = s1 + v.z, s3 = s2 + v.w;
    lds[t] = s3;
    __syncthreads();
    int val = s3;
    for (int off = 1; off < 256; off <<= 1) {
        int u = (t >= off) ? lds[t - off] : 0;
        __syncthreads();
        val += u; lds[t] = val;
        __syncthreads();
    }
    int excl = val - s3;
    int4 o; o.x = excl + s0; o.y = excl + s1; o.z = excl + s2; o.w = excl + s3;
    *(int4*)(data + base + t * 4) = o;
    if (t == 255) bsum[blockIdx.x] = val;
}

__global__ void scan_mid_k(int* __restrict__ bsum, int nb)
{
    __shared__ int lds[64];
    int t = threadIdx.x;
    int v = (t < nb) ? bsum[t] : 0;
    lds[t] = v;
    __syncthreads();
    int val = v;
    for (int off = 1; off < 64; off <<= 1) {
        int u = (t >= off) ? lds[t - off] : 0;
        __syncthreads();
        val += u; lds[t] = val;
        __syncthreads();
    }
    if (t < nb) bsum[t] = val - v;   // exclusive
}

__global__ __launch_bounds__(256) void scan_add_k(const int* __restrict__ inc, const int* __restrict__ bsum,
                                                  int* __restrict__ rowptr, int* __restrict__ cur)
{
    int t = threadIdx.x;
    int base = blockIdx.x * 1024;
    int off = bsum[blockIdx.x];
    int4 v = *(const int4*)(inc + base + t * 4);
    int idx = base + t * 4;
    rowptr[idx + 1] = v.x + off; rowptr[idx + 2] = v.y + off;
    rowptr[idx + 3] = v.z + off; rowptr[idx + 4] = v.w + off;
    cur[idx + 1] = v.x + off; cur[idx + 2] = v.y + off;
    cur[idx + 3] = v.z + off; cur[idx + 4] = v.w + off;
    if (blockIdx.x == 0 && t == 0) { rowptr[0] = 0; cur[0] = 0; }
}

__global__ void fill1_k(const int* __restrict__ src, const int* __restrict__ dst,
                        int* __restrict__ cur, int* __restrict__ csr)
{
    int e = blockIdx.x * 256 + threadIdx.x;
    if (e >= EE) return;
    int pos = atomicAdd(&cur[dst[e]], 1);
    csr[pos] = src[e];
}

__global__ void dinv_k(const int* __restrict__ rowptr, float* __restrict__ dinv, int n)
{
    int i = blockIdx.x * 256 + threadIdx.x;
    if (i >= n) return;
    float deg = (float)(rowptr[i + 1] - rowptr[i]) + 1.0f;   // + self loop
    dinv[i] = 1.0f / sqrtf(deg);
}

// ---------------- GCN aggregation over prescaled rows, fused bias+relu+score-projection ----
// half-wave (32 lanes) per node, float4 per lane. XWs rows are already dinv-scaled.
// XCD-swizzled block index for per-graph L2 locality.
__global__ __launch_bounds__(256) void agg_feat_k(const float4* __restrict__ XWs,
                                                  const int* __restrict__ rowptr, const int* __restrict__ csr,
                                                  const float* __restrict__ dinv, const float* __restrict__ bias,
                                                  const float* __restrict__ Ws,
                                                  float* __restrict__ hout, float* __restrict__ hss, int n)
{
    int nblk = gridDim.x;                       // multiple of 8
    int bid  = blockIdx.x;
    int b    = (bid & 7) * (nblk >> 3) + (bid >> 3);   // XCD chunk swizzle
    int half = threadIdx.x >> 5;
    int lane = threadIdx.x & 31;
    int node = (b << 3) + half;
    if (node >= n) return;
    const float4* Xf = XWs + lane;              // row r at Xf[r*32]

    float4 A = make_float4(0.f, 0.f, 0.f, 0.f), B = A, C = A, D = A;
    int p0 = rowptr[node], p1 = rowptr[node + 1];
    int p = p0;
    for (; p + 8 <= p1; p += 8) {
        int s0 = csr[p], s1 = csr[p + 1], s2 = csr[p + 2], s3 = csr[p + 3];
        int s4 = csr[p + 4], s5 = csr[p + 5], s6 = csr[p + 6], s7 = csr[p + 7];
        float4 v0 = Xf[(size_t)s0 << 5], v1 = Xf[(size_t)s1 << 5];
        float4 v2 = Xf[(size_t)s2 << 5], v3 = Xf[(size_t)s3 << 5];
        float4 v4 = Xf[(size_t)s4 << 5], v5 = Xf[(size_t)s5 << 5];
        float4 v6 = Xf[(size_t)s6 << 5], v7 = Xf[(size_t)s7 << 5];
        A = f4add(A, v0); B = f4add(B, v1); C = f4add(C, v2); D = f4add(D, v3);
        A = f4add(A, v4); B = f4add(B, v5); C = f4add(C, v6); D = f4add(D, v7);
    }
    for (; p + 4 <= p1; p += 4) {
        int s0 = csr[p], s1 = csr[p + 1], s2 = csr[p + 2], s3 = csr[p + 3];
        float4 v0 = Xf[(size_t)s0 << 5], v1 = Xf[(size_t)s1 << 5];
        float4 v2 = Xf[(size_t)s2 << 5], v3 = Xf[(size_t)s3 << 5];
        A = f4add(A, v0); B = f4add(B, v1); C = f4add(C, v2); D = f4add(D, v3);
    }
    for (; p < p1; ++p) {
        int s = csr[p];
        A = f4add(A, Xf[(size_t)s << 5]);
    }
    float4 acc = f4add(f4add(A, B), f4add(C, D));
    acc = f4add(acc, Xf[(size_t)node << 5]);    // self term (prescaled = dinv_d * XW_d)

    float dd = dinv[node];
    float4 bb = *(const float4*)(bias + (lane << 2));
    acc.x = fmaxf(fmaf(acc.x, dd, bb.x), 0.f);
    acc.y = fmaxf(fmaf(acc.y, dd, bb.y), 0.f);
    acc.z = fmaxf(fmaf(acc.z, dd, bb.z), 0.f);
    acc.w = fmaxf(fmaf(acc.w, dd, bb.w), 0.f);
    *(float4*)(hout + ((size_t)node << 7) + (lane << 2)) = acc;

    float4 wsv = *(const float4*)(Ws + (lane << 2));
    float pq = acc.x * wsv.x + acc.y * wsv.y + acc.z * wsv.z + acc.w * wsv.w;
#pragma unroll
    for (int off = 16; off > 0; off >>= 1) pq += __shfl_down(pq, off, 32);
    if (lane == 0) hss[node] = dd * pq;         // prescaled score: dinv_d * hs_d
}

// score[d] = dinv_d * (sum_in hss[s] + hss[d]) + bs   (hss already dinv-scaled)
__global__ void score_k(const int* __restrict__ rowptr, const int* __restrict__ csr,
                        const float* __restrict__ dinv, const float* __restrict__ hss,
                        const float* __restrict__ bsp, float* __restrict__ score, int n)
{
    int i = blockIdx.x * 256 + threadIdx.x;
    if (i >= n) return;
    float a = 0.f, b = 0.f, c = 0.f, e = 0.f;
    int p0 = rowptr[i], p1 = rowptr[i + 1];
    int p = p0;
    for (; p + 8 <= p1; p += 8) {
        int s0 = csr[p], s1 = csr[p + 1], s2 = csr[p + 2], s3 = csr[p + 3];
        int s4 = csr[p + 4], s5 = csr[p + 5], s6 = csr[p + 6], s7 = csr[p + 7];
        a += hss[s0]; b += hss[s1]; c += hss[s2]; e += hss[s3];
        a += hss[s4]; b += hss[s5]; c += hss[s6]; e += hss[s7];
    }
    for (; p + 4 <= p1; p += 4) {
        int s0 = csr[p], s1 = csr[p + 1], s2 = csr[p + 2], s3 = csr[p + 3];
        a += hss[s0]; b += hss[s1]; c += hss[s2]; e += hss[s3];
    }
    for (; p < p1; ++p) a += hss[csr[p]];
    float acc = (a + b) + (c + e) + hss[i];
    score[i] = fmaf(acc, dinv[i], bsp[0]);
}

// ---------------- per-graph top-k via bitonic sort (ties: lower index first) ----------------
template <int NNE, int KK, bool MARK>
__global__ void topk_k(const float* __restrict__ score, int* __restrict__ perm,
                       int* __restrict__ kept, int* __restrict__ nmap)
{
    __shared__ unsigned long long keys[NNE];
    int t = threadIdx.x;
    int g = blockIdx.x;
    float s = score[g * NNE + t];
    unsigned u = __float_as_uint(s);
    u = (u & 0x80000000u) ? ~u : (u | 0x80000000u);           // monotone map
    keys[t] = (((unsigned long long)u) << 32) | (unsigned)(NNE - 1 - t);
    __syncthreads();
    for (int k = 2; k <= NNE; k <<= 1) {
        for (int j = k >> 1; j > 0; j >>= 1) {
            int ixj = t ^ j;
            if (ixj > t) {
                unsigned long long a = keys[t], b = keys[ixj];
                bool up = ((t & k) == 0);
                if ((a > b) == up) { keys[t] = b; keys[ixj] = a; }
            }
            __syncthreads();
        }
    }
    if (t < KK) {
        int idx = NNE - 1 - (int)(keys[NNE - 1 - t] & 0xFFFFFFFFu);
        int o = g * NNE + idx;                 // global old id, rank order
        perm[g * KK + t] = o;
        if (MARK) {
            kept[o] = 1;
            nmap[o] = g * KK + t;
        }
    }
}

__global__ void gather_k(const float* __restrict__ h, const float* __restrict__ score,
                         const int* __restrict__ perm, float* __restrict__ xn, int m)
{
    int nblk = gridDim.x;
    int bid  = blockIdx.x;
    int b    = (bid & 7) * (nblk >> 3) + (bid >> 3);   // XCD chunk swizzle
    int gid = b * 256 + threadIdx.x;
    int node = gid >> 5, f4 = (gid & 31) << 2;
    if (node >= m) return;
    int o = perm[node];
    float tv = tanhf(score[o]);
    float4 v = *(const float4*)(h + ((size_t)o << 7) + f4);
    v.x *= tv; v.y *= tv; v.z *= tv; v.w *= tv;
    *(float4*)(xn + ((size_t)node << 7) + f4) = v;
}

template <int KN>
__global__ __launch_bounds__(128) void readout_k(const float* __restrict__ xn, float* __restrict__ xo)
{
    int g = blockIdx.x, t = threadIdx.x;
    const float* bp = xn + (size_t)g * KN * HH;
    float mx = -INFINITY, sm = 0.f;
    for (int r = 0; r < KN; ++r) {
        float v = bp[(size_t)r * HH + t];
        mx = fmaxf(mx, v);
        sm += v;
    }
    xo[g * 256 + t] = mx;
    xo[g * 256 + 128 + t] = sm * (1.0f / (float)KN);
}

// level-2 CSR over surviving edges (kept[src] & kept[dst]); ids remapped via nmap
__global__ void count2_k(const int* __restrict__ src, const int* __restrict__ dst,
                         const int* __restrict__ kept, const int* __restrict__ nmap, int* __restrict__ cnt)
{
    int e = blockIdx.x * 256 + threadIdx.x;
    if (e >= EE) return;
    int s = src[e], d = dst[e];
    if (kept[s] && kept[d]) atomicAdd(&cnt[nmap[d]], 1);
}

__global__ void fill2_k(const int* __restrict__ src, const int* __restrict__ dst,
                        const int* __restrict__ kept, const int* __restrict__ nmap,
                        int* __restrict__ cur, int* __restrict__ csr)
{
    int e = blockIdx.x * 256 + threadIdx.x;
    if (e >= EE) return;
    int s = src[e], d = dst[e];
    if (kept[s] && kept[d]) {
        int pos = atomicAdd(&cur[nmap[d]], 1);
        csr[pos] = nmap[s];
    }
}

// ---------------- head: z=x1+x2; relu(z@Wl1+bl1); @Wl2+bl2 ----------------
__global__ __launch_bounds__(128) void mlp_k(const float* __restrict__ x1, const float* __restrict__ x2,
                                             const float* __restrict__ Wl1, const float* __restrict__ bl1,
                                             const float* __restrict__ Wl2, const float* __restrict__ bl2,
                                             float* __restrict__ out)
{
    __shared__ float z[256];
    __shared__ float red[128];
    int g = blockIdx.x, t = threadIdx.x;
    z[t]       = x1[g * 256 + t]       + x2[g * 256 + t];
    z[t + 128] = x1[g * 256 + 128 + t] + x2[g * 256 + 128 + t];
    __syncthreads();
    float acc = bl1[t];
    for (int k = 0; k < 256; ++k) acc = fmaf(z[k], Wl1[k * 128 + t], acc);
    float zz = fmaxf(acc, 0.f);
    red[t] = zz * Wl2[t];
    __syncthreads();
    for (int off = 64; off > 0; off >>= 1) {
        if (t < off) red[t] += red[t + off];
        __syncthreads();
    }
    if (t == 0) out[g] = red[0] + bl2[0];
}

// ---------------- launch ----------------
extern "C" void kernel_launch(void* const* d_in, const int* in_sizes, int n_in,
                              void* d_out, int out_size, void* d_ws, size_t ws_size,
                              hipStream_t stream)
{
    const float* x   = (const float*)d_in[0];
    const int*   src = (const int*)d_in[1];
    const int*   dst = (const int*)d_in[2];
    const float* W1  = (const float*)d_in[3];
    const float* b1  = (const float*)d_in[4];
    const float* Ws1 = (const float*)d_in[5];
    const float* bs1 = (const float*)d_in[6];
    const float* W2  = (const float*)d_in[7];
    const float* b2  = (const float*)d_in[8];
    const float* Ws2 = (const float*)d_in[9];
    const float* bs2 = (const float*)d_in[10];
    const float* Wl1 = (const float*)d_in[11];
    const float* bl1 = (const float*)d_in[12];
    const float* Wl2 = (const float*)d_in[13];
    const float* bl2 = (const float*)d_in[14];
    float* out = (float*)d_out;
    char* ws = (char*)d_ws;

    // big regions (reused over time)
    float* XW1 = (float*)(ws);                        // 32MB [0,32M)   (dinv-prescaled)
    float* h1  = (float*)(ws + ((size_t)32 << 20));   // 32MB [32M,64M)
    float* xn  = XW1;                                 // 16MB [0,16M)    (after agg1)
    float* XW2 = (float*)(ws + ((size_t)16 << 20));   // 16MB [16M,32M)  (after agg1)
    float* h2  = h1;                                  // 16MB [32M,48M)  (after gather1)
    float* xn2 = (float*)(ws + ((size_t)48 << 20));   // 8MB  [48M,56M)
    size_t SB = (size_t)64 << 20;
    auto alloc = [&](size_t bytes) { char* p = ws + SB; SB += (bytes + 255) & ~(size_t)255; return p; };
    float* hss1   = (float*)alloc(NN1 * 4);
    float* score1 = (float*)alloc(NN1 * 4);
    float* dinv1  = (float*)alloc(NN1 * 4);
    int* rowptr1  = (int*)alloc((NN1 + 1) * 4);
    int* cur1     = (int*)alloc((NN1 + 1) * 4);
    int* cnt1     = (int*)alloc(NN1 * 4);
    int* kept     = (int*)alloc(NN1 * 4);
    int* nmap     = (int*)alloc(NN1 * 4);
    int* csr1     = (int*)alloc((size_t)EE * 4);
    int* perm1    = (int*)alloc(M1 * 4);
    float* hss2   = (float*)alloc(M1 * 4);
    float* score2 = (float*)alloc(M1 * 4);
    float* dinv2  = (float*)alloc(M1 * 4);
    int* rowptr2  = (int*)alloc((M1 + 1) * 4);
    int* cur2     = (int*)alloc((M1 + 1) * 4);
    int* cnt2     = (int*)alloc(M1 * 4);
    int* csr2     = (int*)alloc((size_t)EE * 4);
    int* perm2    = (int*)alloc(M2 * 4);
    float* x1     = (float*)alloc(GG * 256 * 4);
    float* x2     = (float*)alloc(GG * 256 * 4);
    int* bsum     = (int*)alloc(64 * 4);
    (void)ws_size; (void)in_sizes; (void)n_in; (void)out_size;

    // ---- level-1 CSR + dinv (independent of features) ----
    hipMemsetAsync(cnt1, 0, NN1 * 4, stream);
    count1_k<<<EE / 256, 256, 0, stream>>>(dst, cnt1);
    scan_block_k<<<NN1 / 1024, 256, 0, stream>>>(cnt1, bsum);
    scan_mid_k<<<1, 64, 0, stream>>>(bsum, NN1 / 1024);
    scan_add_k<<<NN1 / 1024, 256, 0, stream>>>(cnt1, bsum, rowptr1, cur1);
    fill1_k<<<EE / 256, 256, 0, stream>>>(src, dst, cur1, csr1);
    dinv_k<<<NN1 / 256, 256, 0, stream>>>(rowptr1, dinv1, NN1);
    // ---- level 1: conv (dinv-prescaled XW) ----
    gemm_f32_128<<<NN1 / 128, 256, 0, stream>>>(x, W1, dinv1, XW1);
    agg_feat_k<<<NN1 / 8, 256, 0, stream>>>((const float4*)XW1, rowptr1, csr1, dinv1, b1, Ws1, h1, hss1, NN1);
    // ---- pool 1 ----
    score_k<<<NN1 / 256, 256, 0, stream>>>(rowptr1, csr1, dinv1, hss1, bs1, score1, NN1);
    hipMemsetAsync(kept, 0, NN1 * 4, stream);
    topk_k<1024, 512, true><<<GG, 1024, 0, stream>>>(score1, perm1, kept, nmap);
    gather_k<<<(M1 * 32) / 256, 256, 0, stream>>>(h1, score1, perm1, xn, M1);
    readout_k<K1><<<GG, 128, 0, stream>>>(xn, x1);
    // ---- level 2 CSR ----
    hipMemsetAsync(cnt2, 0, M1 * 4, stream);
    count2_k<<<EE / 256, 256, 0, stream>>>(src, dst, kept, nmap, cnt2);
    scan_block_k<<<M1 / 1024, 256, 0, stream>>>(cnt2, bsum);
    scan_mid_k<<<1, 64, 0, stream>>>(bsum, M1 / 1024);
    scan_add_k<<<M1 / 1024, 256, 0, stream>>>(cnt2, bsum, rowptr2, cur2);
    fill2_k<<<EE / 256, 256, 0, stream>>>(src, dst, kept, nmap, cur2, csr2);
    dinv_k<<<M1 / 256, 256, 0, stream>>>(rowptr2, dinv2, M1);
    // ---- level 2: conv ----
    gemm_f32_128<<<M1 / 128, 256, 0, stream>>>(xn, W2, dinv2, XW2);
    agg_feat_k<<<M1 / 8, 256, 0, stream>>>((const float4*)XW2, rowptr2, csr2, dinv2, b2, Ws2, h2, hss2, M1);
    // ---- pool 2 ----
    score_k<<<M1 / 256, 256, 0, stream>>>(rowptr2, csr2, dinv2, hss2, bs2, score2, M1);
    topk_k<512, 256, false><<<GG, 512, 0, stream>>>(score2, perm2, nullptr, nullptr);
    gather_k<<<(M2 * 32) / 256, 256, 0, stream>>>(h2, score2, perm2, xn2, M2);
    readout_k<K2><<<GG, 128, 0, stream>>>(xn2, x2);
    // ---- head ----
    mlp_k<<<GG, 128, 0, stream>>>(x1, x2, Wl1, bl1, Wl2, bl2, out);
}

// Round 4
// 299.897 us; speedup vs baseline: 1.2942x; 1.0069x over previous
//
#include <hip/hip_runtime.h>
#include <math.h>

// ---------------- problem constants ----------------
constexpr int NN1 = 65536;      // level-0 nodes
constexpr int EE  = 1048576;    // edges
constexpr int GG  = 64;         // graphs
constexpr int HH  = 128;        // hidden
constexpr int NPG = 1024;       // nodes/graph level-0
constexpr int EPG = 16384;      // edges/graph
constexpr int K1  = 512;        // keep after pool1 (per graph)
constexpr int M1  = GG * K1;    // 32768
constexpr int K2  = 256;        // keep after pool2
constexpr int M2  = GG * K2;    // 16384

__device__ __forceinline__ float4 f4add(float4 a, float4 b)
{
    a.x += b.x; a.y += b.y; a.z += b.z; a.w += b.w; return a;
}

// ---------------- GEMM: C[r] = dinv[r] * (A[r] @ W), fp32 ----------------
// 256 threads; tile 128 rows x 128 cols; thread: 4 rows x 16 cols.
// W staged in LDS in two 64-row chunks; col-group cg at float offset cg*20
// -> per-read banks {0,20,8,28,16,4,24,12}+q*4: full 32-bank partition, conflict-free.
// A loads software-pipelined (xn_ prefetch). dinv computed from rbeg/rend.
__global__ __launch_bounds__(256, 4) void gemm_f32_128(const float* __restrict__ A,
                                                       const float* __restrict__ W,
                                                       const int* __restrict__ rbeg,
                                                       const int* __restrict__ rend,
                                                       float* __restrict__ C)
{
    __shared__ float Wl[64 * 160];   // 40960 B
    const int t    = threadIdx.x;
    const int rowg = t >> 3;         // 0..31
    const int cg   = t & 7;          // 0..7
    const int r0   = (blockIdx.x << 7) + rowg;

    const float* Ar0 = A + ((size_t)r0 << 7);
    const float* Ar1 = Ar0 + (32 << 7);
    const float* Ar2 = Ar1 + (32 << 7);
    const float* Ar3 = Ar2 + (32 << 7);

    float acc[4][16];
#pragma unroll
    for (int i = 0; i < 4; ++i)
#pragma unroll
        for (int j = 0; j < 16; ++j) acc[i][j] = 0.f;

    // ---- stage chunk 0 ----
    {
        const float4* Wg = (const float4*)W;
#pragma unroll
        for (int i = 0; i < 8; ++i) {
            int idx = t + (i << 8);
            int k   = idx >> 5;
            int c4  = (idx & 31) << 2;
            *(float4*)&Wl[k * 160 + (c4 >> 4) * 20 + (c4 & 15)] = Wg[idx];
        }
    }
    float4 xc0 = *(const float4*)(Ar0), xc1 = *(const float4*)(Ar1);
    float4 xc2 = *(const float4*)(Ar2), xc3 = *(const float4*)(Ar3);
    __syncthreads();

    const float* wbase = &Wl[cg * 20];

#pragma unroll 1
    for (int k0 = 0; k0 < 64; k0 += 4) {
        float4 xn0 = *(const float4*)(Ar0 + k0 + 4);
        float4 xn1 = *(const float4*)(Ar1 + k0 + 4);
        float4 xn2 = *(const float4*)(Ar2 + k0 + 4);
        float4 xn3 = *(const float4*)(Ar3 + k0 + 4);
#pragma unroll
        for (int kk = 0; kk < 4; ++kk) {
            const float* wr = wbase + (k0 + kk) * 160;
            float wv[16];
#pragma unroll
            for (int j = 0; j < 16; j += 4) *(float4*)&wv[j] = *(const float4*)(wr + j);
            float x0 = ((const float*)&xc0)[kk], x1 = ((const float*)&xc1)[kk];
            float x2 = ((const float*)&xc2)[kk], x3 = ((const float*)&xc3)[kk];
#pragma unroll
            for (int j = 0; j < 16; ++j) {
                acc[0][j] = fmaf(x0, wv[j], acc[0][j]);
                acc[1][j] = fmaf(x1, wv[j], acc[1][j]);
                acc[2][j] = fmaf(x2, wv[j], acc[2][j]);
                acc[3][j] = fmaf(x3, wv[j], acc[3][j]);
            }
        }
        xc0 = xn0; xc1 = xn1; xc2 = xn2; xc3 = xn3;
    }
    __syncthreads();
    // ---- stage chunk 1 ----
    {
        const float4* Wg = (const float4*)(W + 64 * 128);
#pragma unroll
        for (int i = 0; i < 8; ++i) {
            int idx = t + (i << 8);
            int k   = idx >> 5;
            int c4  = (idx & 31) << 2;
            *(float4*)&Wl[k * 160 + (c4 >> 4) * 20 + (c4 & 15)] = Wg[idx];
        }
    }
    __syncthreads();

#pragma unroll 1
    for (int k0 = 64; k0 < 128; k0 += 4) {
        bool pf = (k0 < 124);
        float4 xn0, xn1, xn2, xn3;
        if (pf) {
            xn0 = *(const float4*)(Ar0 + k0 + 4);
            xn1 = *(const float4*)(Ar1 + k0 + 4);
            xn2 = *(const float4*)(Ar2 + k0 + 4);
            xn3 = *(const float4*)(Ar3 + k0 + 4);
        }
#pragma unroll
        for (int kk = 0; kk < 4; ++kk) {
            const float* wr = wbase + (k0 - 64 + kk) * 160;
            float wv[16];
#pragma unroll
            for (int j = 0; j < 16; j += 4) *(float4*)&wv[j] = *(const float4*)(wr + j);
            float x0 = ((const float*)&xc0)[kk], x1 = ((const float*)&xc1)[kk];
            float x2 = ((const float*)&xc2)[kk], x3 = ((const float*)&xc3)[kk];
#pragma unroll
            for (int j = 0; j < 16; ++j) {
                acc[0][j] = fmaf(x0, wv[j], acc[0][j]);
                acc[1][j] = fmaf(x1, wv[j], acc[1][j]);
                acc[2][j] = fmaf(x2, wv[j], acc[2][j]);
                acc[3][j] = fmaf(x3, wv[j], acc[3][j]);
            }
        }
        if (pf) { xc0 = xn0; xc1 = xn1; xc2 = xn2; xc3 = xn3; }
    }

    // epilogue: scale by dinv[r] = 1/sqrt(deg+1), write
#pragma unroll
    for (int i = 0; i < 4; ++i) {
        int r = r0 + (i << 5);
        float deg = (float)(rend[r] - rbeg[r]) + 1.0f;
        float sc = 1.0f / sqrtf(deg);
        float* cp = C + ((size_t)r << 7) + (cg << 4);
#pragma unroll
        for (int j = 0; j < 16; j += 4) {
            float4 v;
            v.x = acc[i][j] * sc; v.y = acc[i][j + 1] * sc;
            v.z = acc[i][j + 2] * sc; v.w = acc[i][j + 3] * sc;
            *(float4*)(cp + j) = v;
        }
    }
}

// ---------------- per-graph CSR build, level 1 (count+scan+fill in one block) ----------
__global__ __launch_bounds__(1024) void build_csr1_k(const int* __restrict__ src, const int* __restrict__ dst,
                                                     int* __restrict__ rbeg, int* __restrict__ rend,
                                                     int* __restrict__ csr)
{
    __shared__ int cnt[NPG];
    int t = threadIdx.x, g = blockIdx.x;
    int ebase = g * EPG;
    cnt[t] = 0;
    __syncthreads();
#pragma unroll
    for (int k = 0; k < EPG / 1024; ++k) {
        int d = dst[ebase + t + k * 1024] & (NPG - 1);
        atomicAdd(&cnt[d], 1);
    }
    __syncthreads();
    int deg0 = cnt[t];
    int val = deg0;
    for (int off = 1; off < NPG; off <<= 1) {
        int u = (t >= off) ? cnt[t - off] : 0;
        __syncthreads();
        val += u; cnt[t] = val;
        __syncthreads();
    }
    int node = g * NPG + t;
    rbeg[node] = ebase + val - deg0;
    rend[node] = ebase + val;
    cnt[t] = val - deg0;
    __syncthreads();
#pragma unroll
    for (int k = 0; k < EPG / 1024; ++k) {
        int e = ebase + t + k * 1024;
        int d = dst[e] & (NPG - 1);
        int pos = atomicAdd(&cnt[d], 1);
        csr[ebase + pos] = src[e];
    }
}

// ---------------- per-graph CSR build, level 2 (prune via nmap, remap ids) -------------
__global__ __launch_bounds__(1024) void build_csr2_k(const int* __restrict__ src, const int* __restrict__ dst,
                                                     const int* __restrict__ nmap,
                                                     int* __restrict__ rbeg, int* __restrict__ rend,
                                                     int* __restrict__ csr)
{
    __shared__ int cnt[K1];
    int t = threadIdx.x, g = blockIdx.x;
    int ebase = g * EPG;
    if (t < K1) cnt[t] = 0;
    __syncthreads();
    int ns[EPG / 1024], nd[EPG / 1024];
#pragma unroll
    for (int k = 0; k < EPG / 1024; ++k) {
        int e = ebase + t + k * 1024;
        ns[k] = nmap[src[e]];
        nd[k] = nmap[dst[e]];
        if (ns[k] >= 0 && nd[k] >= 0) atomicAdd(&cnt[nd[k] & (K1 - 1)], 1);
    }
    __syncthreads();
    int deg0 = 0, val = 0;
    if (t < K1) { deg0 = cnt[t]; val = deg0; }
    for (int off = 1; off < K1; off <<= 1) {
        int u = (t < K1 && t >= off) ? cnt[t - off] : 0;
        __syncthreads();
        if (t < K1) { val += u; cnt[t] = val; }
        __syncthreads();
    }
    if (t < K1) {
        int node = g * K1 + t;
        rbeg[node] = ebase + val - deg0;
        rend[node] = ebase + val;
        cnt[t] = val - deg0;
    }
    __syncthreads();
#pragma unroll
    for (int k = 0; k < EPG / 1024; ++k) {
        if (ns[k] >= 0 && nd[k] >= 0) {
            int pos = atomicAdd(&cnt[nd[k] & (K1 - 1)], 1);
            csr[ebase + pos] = ns[k];
        }
    }
}

// ---------------- GCN aggregation over prescaled rows, fused bias+relu+score-projection ----
// half-wave (32 lanes) per node, float4 per lane; dinv from rbeg/rend; XCD swizzle.
__global__ __launch_bounds__(256) void agg_feat_k(const float4* __restrict__ XWs,
                                                  const int* __restrict__ rbeg, const int* __restrict__ rend,
                                                  const int* __restrict__ csr,
                                                  const float* __restrict__ bias, const float* __restrict__ Ws,
                                                  float* __restrict__ hout, float* __restrict__ hss, int n)
{
    int nblk = gridDim.x;                       // multiple of 8
    int bid  = blockIdx.x;
    int b    = (bid & 7) * (nblk >> 3) + (bid >> 3);   // XCD chunk swizzle
    int half = threadIdx.x >> 5;
    int lane = threadIdx.x & 31;
    int node = (b << 3) + half;
    if (node >= n) return;
    const float4* Xf = XWs + lane;              // row r at Xf[r*32]

    float4 A = make_float4(0.f, 0.f, 0.f, 0.f), B = A, C = A, D = A;
    int p0 = rbeg[node], p1 = rend[node];
    int p = p0;
    for (; p + 8 <= p1; p += 8) {
        int s0 = csr[p], s1 = csr[p + 1], s2 = csr[p + 2], s3 = csr[p + 3];
        int s4 = csr[p + 4], s5 = csr[p + 5], s6 = csr[p + 6], s7 = csr[p + 7];
        float4 v0 = Xf[(size_t)s0 << 5], v1 = Xf[(size_t)s1 << 5];
        float4 v2 = Xf[(size_t)s2 << 5], v3 = Xf[(size_t)s3 << 5];
        float4 v4 = Xf[(size_t)s4 << 5], v5 = Xf[(size_t)s5 << 5];
        float4 v6 = Xf[(size_t)s6 << 5], v7 = Xf[(size_t)s7 << 5];
        A = f4add(A, v0); B = f4add(B, v1); C = f4add(C, v2); D = f4add(D, v3);
        A = f4add(A, v4); B = f4add(B, v5); C = f4add(C, v6); D = f4add(D, v7);
    }
    for (; p + 4 <= p1; p += 4) {
        int s0 = csr[p], s1 = csr[p + 1], s2 = csr[p + 2], s3 = csr[p + 3];
        float4 v0 = Xf[(size_t)s0 << 5], v1 = Xf[(size_t)s1 << 5];
        float4 v2 = Xf[(size_t)s2 << 5], v3 = Xf[(size_t)s3 << 5];
        A = f4add(A, v0); B = f4add(B, v1); C = f4add(C, v2); D = f4add(D, v3);
    }
    for (; p < p1; ++p) {
        int s = csr[p];
        A = f4add(A, Xf[(size_t)s << 5]);
    }
    float4 acc = f4add(f4add(A, B), f4add(C, D));
    acc = f4add(acc, Xf[(size_t)node << 5]);    // self term (prescaled)

    float dd = 1.0f / sqrtf((float)(p1 - p0) + 1.0f);
    float4 bb = *(const float4*)(bias + (lane << 2));
    acc.x = fmaxf(fmaf(acc.x, dd, bb.x), 0.f);
    acc.y = fmaxf(fmaf(acc.y, dd, bb.y), 0.f);
    acc.z = fmaxf(fmaf(acc.z, dd, bb.z), 0.f);
    acc.w = fmaxf(fmaf(acc.w, dd, bb.w), 0.f);
    *(float4*)(hout + ((size_t)node << 7) + (lane << 2)) = acc;

    float4 wsv = *(const float4*)(Ws + (lane << 2));
    float pq = acc.x * wsv.x + acc.y * wsv.y + acc.z * wsv.z + acc.w * wsv.w;
#pragma unroll
    for (int off = 16; off > 0; off >>= 1) pq += __shfl_down(pq, off, 32);
    if (lane == 0) hss[node] = dd * pq;         // prescaled score
}

// ---------------- fused score + per-graph top-k (+ nmap, + tanh(score)) -----------------
template <int NNE, int KK, bool MARK>
__global__ void sctopk_k(const int* __restrict__ rbeg, const int* __restrict__ rend,
                         const int* __restrict__ csr, const float* __restrict__ hss,
                         const float* __restrict__ bsp,
                         int* __restrict__ perm, float* __restrict__ tsel,
                         int* __restrict__ nmap)
{
    __shared__ unsigned long long keys[NNE];
    int t = threadIdx.x, g = blockIdx.x;
    int node = g * NNE + t;
    int p0 = rbeg[node], p1 = rend[node];
    float a = 0.f, b = 0.f, c = 0.f, e = 0.f;
    int p = p0;
    for (; p + 8 <= p1; p += 8) {
        int s0 = csr[p], s1 = csr[p + 1], s2 = csr[p + 2], s3 = csr[p + 3];
        int s4 = csr[p + 4], s5 = csr[p + 5], s6 = csr[p + 6], s7 = csr[p + 7];
        a += hss[s0]; b += hss[s1]; c += hss[s2]; e += hss[s3];
        a += hss[s4]; b += hss[s5]; c += hss[s6]; e += hss[s7];
    }
    for (; p + 4 <= p1; p += 4) {
        int s0 = csr[p], s1 = csr[p + 1], s2 = csr[p + 2], s3 = csr[p + 3];
        a += hss[s0]; b += hss[s1]; c += hss[s2]; e += hss[s3];
    }
    for (; p < p1; ++p) a += hss[csr[p]];
    float dd = 1.0f / sqrtf((float)(p1 - p0) + 1.0f);
    float s = fmaf((a + b) + (c + e) + hss[node], dd, bsp[0]);

    unsigned u = __float_as_uint(s);
    u = (u & 0x80000000u) ? ~u : (u | 0x80000000u);           // monotone map
    keys[t] = (((unsigned long long)u) << 32) | (unsigned)(NNE - 1 - t);
    __syncthreads();
    for (int k = 2; k <= NNE; k <<= 1) {
        for (int j = k >> 1; j > 0; j >>= 1) {
            int ixj = t ^ j;
            if (ixj > t) {
                unsigned long long ka = keys[t], kb = keys[ixj];
                bool up = ((t & k) == 0);
                if ((ka > kb) == up) { keys[t] = kb; keys[ixj] = ka; }
            }
            __syncthreads();
        }
    }
    unsigned long long key = keys[NNE - 1 - t];   // rank t
    int idx = NNE - 1 - (int)(key & 0xFFFFFFFFu);
    if (t < KK) {
        perm[g * KK + t] = g * NNE + idx;
        unsigned uu = (unsigned)(key >> 32);
        float sc = __uint_as_float((uu & 0x80000000u) ? (uu ^ 0x80000000u) : ~uu);
        tsel[g * KK + t] = tanhf(sc);
        if (MARK) nmap[g * NNE + idx] = g * KK + t;
    } else if (MARK) {
        nmap[g * NNE + idx] = -1;
    }
}

// ---------------- gather kept rows * tanh(score) ----------------
__global__ void gather_k(const float* __restrict__ h, const float* __restrict__ tsel,
                         const int* __restrict__ perm, float* __restrict__ xn)
{
    int nblk = gridDim.x;
    int bid  = blockIdx.x;
    int b    = (bid & 7) * (nblk >> 3) + (bid >> 3);   // XCD chunk swizzle
    int gid = b * 256 + threadIdx.x;
    int node = gid >> 5, f4 = (gid & 31) << 2;
    int o = perm[node];
    float tv = tsel[node];
    float4 v = *(const float4*)(h + ((size_t)o << 7) + f4);
    v.x *= tv; v.y *= tv; v.z *= tv; v.w *= tv;
    *(float4*)(xn + ((size_t)node << 7) + f4) = v;
}

// ---------------- readout partials: per-128-row chunk {max | sum} ----------------
__global__ __launch_bounds__(128) void readout_p_k(const float* __restrict__ xn, float* __restrict__ part)
{
    int b = blockIdx.x, t = threadIdx.x;
    const float* bp = xn + (size_t)b * (128 * 128);
    float mx = -INFINITY, sm = 0.f;
#pragma unroll 4
    for (int r = 0; r < 128; ++r) {
        float v = bp[r * 128 + t];
        mx = fmaxf(mx, v);
        sm += v;
    }
    part[b * 256 + t] = mx;
    part[b * 256 + 128 + t] = sm;
}

// ---------------- head: combine partials; z=x1+x2; relu(z@Wl1+bl1); @Wl2+bl2 ------------
__global__ __launch_bounds__(128) void mlp_k(const float* __restrict__ part1, const float* __restrict__ part2,
                                             const float* __restrict__ Wl1, const float* __restrict__ bl1,
                                             const float* __restrict__ Wl2, const float* __restrict__ bl2,
                                             float* __restrict__ out)
{
    __shared__ float z[256];
    __shared__ float red[128];
    int g = blockIdx.x, t = threadIdx.x;
    float mx1 = -INFINITY, sm1 = 0.f;
#pragma unroll
    for (int j = 0; j < 4; ++j) {
        mx1 = fmaxf(mx1, part1[(g * 4 + j) * 256 + t]);
        sm1 += part1[(g * 4 + j) * 256 + 128 + t];
    }
    float mx2 = -INFINITY, sm2 = 0.f;
#pragma unroll
    for (int j = 0; j < 2; ++j) {
        mx2 = fmaxf(mx2, part2[(g * 2 + j) * 256 + t]);
        sm2 += part2[(g * 2 + j) * 256 + 128 + t];
    }
    z[t]       = mx1 + mx2;
    z[t + 128] = sm1 * (1.f / 512.f) + sm2 * (1.f / 256.f);
    __syncthreads();
    float acc = bl1[t];
    for (int k = 0; k < 256; ++k) acc = fmaf(z[k], Wl1[k * 128 + t], acc);
    float zz = fmaxf(acc, 0.f);
    red[t] = zz * Wl2[t];
    __syncthreads();
    for (int off = 64; off > 0; off >>= 1) {
        if (t < off) red[t] += red[t + off];
        __syncthreads();
    }
    if (t == 0) out[g] = red[0] + bl2[0];
}

// ---------------- launch ----------------
extern "C" void kernel_launch(void* const* d_in, const int* in_sizes, int n_in,
                              void* d_out, int out_size, void* d_ws, size_t ws_size,
                              hipStream_t stream)
{
    const float* x   = (const float*)d_in[0];
    const int*   src = (const int*)d_in[1];
    const int*   dst = (const int*)d_in[2];
    const float* W1  = (const float*)d_in[3];
    const float* b1  = (const float*)d_in[4];
    const float* Ws1 = (const float*)d_in[5];
    const float* bs1 = (const float*)d_in[6];
    const float* W2  = (const float*)d_in[7];
    const float* b2  = (const float*)d_in[8];
    const float* Ws2 = (const float*)d_in[9];
    const float* bs2 = (const float*)d_in[10];
    const float* Wl1 = (const float*)d_in[11];
    const float* bl1 = (const float*)d_in[12];
    const float* Wl2 = (const float*)d_in[13];
    const float* bl2 = (const float*)d_in[14];
    float* out = (float*)d_out;
    char* ws = (char*)d_ws;

    // big regions (time-multiplexed)
    float* XW1 = (float*)(ws);                        // 32MB [0,32M)   (dinv-prescaled)
    float* h1  = (float*)(ws + ((size_t)32 << 20));   // 32MB [32M,64M)
    float* xn  = XW1;                                 // 16MB [0,16M)    (after agg1)
    float* XW2 = (float*)(ws + ((size_t)16 << 20));   // 16MB [16M,32M)  (after agg1)
    float* h2  = h1;                                  // 16MB [32M,48M)  (after gather1)
    float* xn2 = (float*)(ws + ((size_t)48 << 20));   // 8MB  [48M,56M)
    size_t SB = (size_t)64 << 20;
    auto alloc = [&](size_t bytes) { char* p = ws + SB; SB += (bytes + 255) & ~(size_t)255; return p; };
    int* csr1     = (int*)alloc((size_t)EE * 4);      // also reused as csr2 after sctopk1
    int* rbeg1    = (int*)alloc(NN1 * 4);
    int* rend1    = (int*)alloc(NN1 * 4);
    float* hss1   = (float*)alloc(NN1 * 4);
    int* nmap     = (int*)alloc(NN1 * 4);
    int* perm1    = (int*)alloc(M1 * 4);
    float* tsel1  = (float*)alloc(M1 * 4);
    int* rbeg2    = (int*)alloc(M1 * 4);
    int* rend2    = (int*)alloc(M1 * 4);
    float* hss2   = (float*)alloc(M1 * 4);
    int* perm2    = (int*)alloc(M2 * 4);
    float* tsel2  = (float*)alloc(M2 * 4);
    float* part1  = (float*)alloc(256 * 256 * 4);
    float* part2  = (float*)alloc(128 * 256 * 4);
    int* csr2     = csr1;
    (void)ws_size; (void)in_sizes; (void)n_in; (void)out_size;

    // ---- level 1 ----
    build_csr1_k<<<GG, 1024, 0, stream>>>(src, dst, rbeg1, rend1, csr1);
    gemm_f32_128<<<NN1 / 128, 256, 0, stream>>>(x, W1, rbeg1, rend1, XW1);
    agg_feat_k<<<NN1 / 8, 256, 0, stream>>>((const float4*)XW1, rbeg1, rend1, csr1, b1, Ws1, h1, hss1, NN1);
    sctopk_k<NPG, K1, true><<<GG, NPG, 0, stream>>>(rbeg1, rend1, csr1, hss1, bs1, perm1, tsel1, nmap);
    gather_k<<<(M1 * 32) / 256, 256, 0, stream>>>(h1, tsel1, perm1, xn);
    readout_p_k<<<M1 / 128, 128, 0, stream>>>(xn, part1);
    // ---- level 2 ----
    build_csr2_k<<<GG, 1024, 0, stream>>>(src, dst, nmap, rbeg2, rend2, csr2);
    gemm_f32_128<<<M1 / 128, 256, 0, stream>>>(xn, W2, rbeg2, rend2, XW2);
    agg_feat_k<<<M1 / 8, 256, 0, stream>>>((const float4*)XW2, rbeg2, rend2, csr2, b2, Ws2, h2, hss2, M1);
    sctopk_k<K1, K2, false><<<GG, K1, 0, stream>>>(rbeg2, rend2, csr2, hss2, bs2, perm2, tsel2, nullptr);
    gather_k<<<(M2 * 32) / 256, 256, 0, stream>>>(h2, tsel2, perm2, xn2);
    readout_p_k<<<M2 / 128, 128, 0, stream>>>(xn2, part2);
    // ---- head ----
    mlp_k<<<GG, 128, 0, stream>>>(part1, part2, Wl1, bl1, Wl2, bl2, out);
}

// Round 5
// 219.540 us; speedup vs baseline: 1.7679x; 1.3660x over previous
//
#include <hip/hip_runtime.h>
#include <math.h>

// ---------------- problem constants ----------------
constexpr int NN1 = 65536;      // level-0 nodes
constexpr int EE  = 1048576;    // edges
constexpr int GG  = 64;         // graphs
constexpr int HH  = 128;        // hidden
constexpr int NPG = 1024;       // nodes/graph level-0
constexpr int EPG = 16384;      // edges/graph
constexpr int K1  = 512;        // keep after pool1 (per graph)
constexpr int M1  = GG * K1;    // 32768
constexpr int K2  = 256;        // keep after pool2
constexpr int M2  = GG * K2;    // 16384

__device__ __forceinline__ float4 f4add(float4 a, float4 b)
{
    a.x += b.x; a.y += b.y; a.z += b.z; a.w += b.w; return a;
}

// ---------------- GEMM: C[r] = dinv[r] * (A[r] @ W), fp32 ----------------
// 256 threads; tile 128 rows x 128 cols; thread: 4 rows x 16 cols.
// W staged in LDS in two 64-row chunks (40960 B); col-group cg at float offset cg*20
// -> reads hit banks {0,20,8,28,16,4,24,12}+q*4: full 32-bank partition, conflict-free.
// A loads software-pipelined. NO min-occupancy clamp: R4's (256,4) forced VGPR=64 -> spills
// (WRITE_SIZE 180MB vs 33MB real). Let the allocator pick (~120 VGPR, 4 waves/SIMD).
__global__ __launch_bounds__(256) void gemm_f32_128(const float* __restrict__ A,
                                                    const float* __restrict__ W,
                                                    const int* __restrict__ rbeg,
                                                    const int* __restrict__ rend,
                                                    float* __restrict__ C)
{
    __shared__ float Wl[64 * 160];   // 40960 B
    const int t    = threadIdx.x;
    const int rowg = t >> 3;         // 0..31
    const int cg   = t & 7;          // 0..7
    const int r0   = (blockIdx.x << 7) + rowg;

    const float* Ar0 = A + ((size_t)r0 << 7);
    const float* Ar1 = Ar0 + (32 << 7);
    const float* Ar2 = Ar1 + (32 << 7);
    const float* Ar3 = Ar2 + (32 << 7);

    float acc[4][16];
#pragma unroll
    for (int i = 0; i < 4; ++i)
#pragma unroll
        for (int j = 0; j < 16; ++j) acc[i][j] = 0.f;

    // ---- stage chunk 0 ----
    {
        const float4* Wg = (const float4*)W;
#pragma unroll
        for (int i = 0; i < 8; ++i) {
            int idx = t + (i << 8);
            int k   = idx >> 5;
            int c4  = (idx & 31) << 2;
            *(float4*)&Wl[k * 160 + (c4 >> 4) * 20 + (c4 & 15)] = Wg[idx];
        }
    }
    float4 xc0 = *(const float4*)(Ar0), xc1 = *(const float4*)(Ar1);
    float4 xc2 = *(const float4*)(Ar2), xc3 = *(const float4*)(Ar3);
    __syncthreads();

    const float* wbase = &Wl[cg * 20];

#pragma unroll 1
    for (int k0 = 0; k0 < 64; k0 += 4) {
        float4 xn0 = *(const float4*)(Ar0 + k0 + 4);
        float4 xn1 = *(const float4*)(Ar1 + k0 + 4);
        float4 xn2 = *(const float4*)(Ar2 + k0 + 4);
        float4 xn3 = *(const float4*)(Ar3 + k0 + 4);
#pragma unroll
        for (int kk = 0; kk < 4; ++kk) {
            const float* wr = wbase + (k0 + kk) * 160;
            float x0 = ((const float*)&xc0)[kk], x1 = ((const float*)&xc1)[kk];
            float x2 = ((const float*)&xc2)[kk], x3 = ((const float*)&xc3)[kk];
#pragma unroll
            for (int jh = 0; jh < 16; jh += 8) {
                float wv[8];
                *(float4*)&wv[0] = *(const float4*)(wr + jh);
                *(float4*)&wv[4] = *(const float4*)(wr + jh + 4);
#pragma unroll
                for (int j = 0; j < 8; ++j) {
                    acc[0][jh + j] = fmaf(x0, wv[j], acc[0][jh + j]);
                    acc[1][jh + j] = fmaf(x1, wv[j], acc[1][jh + j]);
                    acc[2][jh + j] = fmaf(x2, wv[j], acc[2][jh + j]);
                    acc[3][jh + j] = fmaf(x3, wv[j], acc[3][jh + j]);
                }
            }
        }
        xc0 = xn0; xc1 = xn1; xc2 = xn2; xc3 = xn3;
    }
    __syncthreads();
    // ---- stage chunk 1 ----
    {
        const float4* Wg = (const float4*)(W + 64 * 128);
#pragma unroll
        for (int i = 0; i < 8; ++i) {
            int idx = t + (i << 8);
            int k   = idx >> 5;
            int c4  = (idx & 31) << 2;
            *(float4*)&Wl[k * 160 + (c4 >> 4) * 20 + (c4 & 15)] = Wg[idx];
        }
    }
    __syncthreads();

#pragma unroll 1
    for (int k0 = 64; k0 < 128; k0 += 4) {
        bool pf = (k0 < 124);
        float4 xn0, xn1, xn2, xn3;
        if (pf) {
            xn0 = *(const float4*)(Ar0 + k0 + 4);
            xn1 = *(const float4*)(Ar1 + k0 + 4);
            xn2 = *(const float4*)(Ar2 + k0 + 4);
            xn3 = *(const float4*)(Ar3 + k0 + 4);
        }
#pragma unroll
        for (int kk = 0; kk < 4; ++kk) {
            const float* wr = wbase + (k0 - 64 + kk) * 160;
            float x0 = ((const float*)&xc0)[kk], x1 = ((const float*)&xc1)[kk];
            float x2 = ((const float*)&xc2)[kk], x3 = ((const float*)&xc3)[kk];
#pragma unroll
            for (int jh = 0; jh < 16; jh += 8) {
                float wv[8];
                *(float4*)&wv[0] = *(const float4*)(wr + jh);
                *(float4*)&wv[4] = *(const float4*)(wr + jh + 4);
#pragma unroll
                for (int j = 0; j < 8; ++j) {
                    acc[0][jh + j] = fmaf(x0, wv[j], acc[0][jh + j]);
                    acc[1][jh + j] = fmaf(x1, wv[j], acc[1][jh + j]);
                    acc[2][jh + j] = fmaf(x2, wv[j], acc[2][jh + j]);
                    acc[3][jh + j] = fmaf(x3, wv[j], acc[3][jh + j]);
                }
            }
        }
        if (pf) { xc0 = xn0; xc1 = xn1; xc2 = xn2; xc3 = xn3; }
    }

    // epilogue: scale by dinv[r] = 1/sqrt(deg+1), write
#pragma unroll
    for (int i = 0; i < 4; ++i) {
        int r = r0 + (i << 5);
        float deg = (float)(rend[r] - rbeg[r]) + 1.0f;
        float sc = 1.0f / sqrtf(deg);
        float* cp = C + ((size_t)r << 7) + (cg << 4);
#pragma unroll
        for (int j = 0; j < 16; j += 4) {
            float4 v;
            v.x = acc[i][j] * sc; v.y = acc[i][j + 1] * sc;
            v.z = acc[i][j + 2] * sc; v.w = acc[i][j + 3] * sc;
            *(float4*)(cp + j) = v;
        }
    }
}

// ---------------- per-graph CSR build, level 1 (count+scan+fill in one block) ----------
__global__ __launch_bounds__(1024) void build_csr1_k(const int* __restrict__ src, const int* __restrict__ dst,
                                                     int* __restrict__ rbeg, int* __restrict__ rend,
                                                     int* __restrict__ csr)
{
    __shared__ int cnt[NPG];
    int t = threadIdx.x, g = blockIdx.x;
    int ebase = g * EPG;
    cnt[t] = 0;
    __syncthreads();
#pragma unroll
    for (int k = 0; k < EPG / 1024; ++k) {
        int d = dst[ebase + t + k * 1024] & (NPG - 1);
        atomicAdd(&cnt[d], 1);
    }
    __syncthreads();
    int deg0 = cnt[t];
    int val = deg0;
    for (int off = 1; off < NPG; off <<= 1) {
        int u = (t >= off) ? cnt[t - off] : 0;
        __syncthreads();
        val += u; cnt[t] = val;
        __syncthreads();
    }
    int node = g * NPG + t;
    rbeg[node] = ebase + val - deg0;
    rend[node] = ebase + val;
    cnt[t] = val - deg0;
    __syncthreads();
#pragma unroll
    for (int k = 0; k < EPG / 1024; ++k) {
        int e = ebase + t + k * 1024;
        int d = dst[e] & (NPG - 1);
        int pos = atomicAdd(&cnt[d], 1);
        csr[ebase + pos] = src[e];
    }
}

// ---------------- per-graph CSR build, level 2 (prune via nmap, remap ids) -------------
__global__ __launch_bounds__(1024) void build_csr2_k(const int* __restrict__ src, const int* __restrict__ dst,
                                                     const int* __restrict__ nmap,
                                                     int* __restrict__ rbeg, int* __restrict__ rend,
                                                     int* __restrict__ csr)
{
    __shared__ int cnt[K1];
    int t = threadIdx.x, g = blockIdx.x;
    int ebase = g * EPG;
    if (t < K1) cnt[t] = 0;
    __syncthreads();
    int ns[EPG / 1024], nd[EPG / 1024];
#pragma unroll
    for (int k = 0; k < EPG / 1024; ++k) {
        int e = ebase + t + k * 1024;
        ns[k] = nmap[src[e]];
        nd[k] = nmap[dst[e]];
        if (ns[k] >= 0 && nd[k] >= 0) atomicAdd(&cnt[nd[k] & (K1 - 1)], 1);
    }
    __syncthreads();
    int deg0 = 0, val = 0;
    if (t < K1) { deg0 = cnt[t]; val = deg0; }
    for (int off = 1; off < K1; off <<= 1) {
        int u = (t < K1 && t >= off) ? cnt[t - off] : 0;
        __syncthreads();
        if (t < K1) { val += u; cnt[t] = val; }
        __syncthreads();
    }
    if (t < K1) {
        int node = g * K1 + t;
        rbeg[node] = ebase + val - deg0;
        rend[node] = ebase + val;
        cnt[t] = val - deg0;
    }
    __syncthreads();
#pragma unroll
    for (int k = 0; k < EPG / 1024; ++k) {
        if (ns[k] >= 0 && nd[k] >= 0) {
            int pos = atomicAdd(&cnt[nd[k] & (K1 - 1)], 1);
            csr[ebase + pos] = ns[k];
        }
    }
}

// ---------------- GCN aggregation over prescaled rows, fused bias+relu+score-projection ----
// half-wave (32 lanes) per node, float4 per lane; dinv from rbeg/rend; XCD swizzle.
__global__ __launch_bounds__(256) void agg_feat_k(const float4* __restrict__ XWs,
                                                  const int* __restrict__ rbeg, const int* __restrict__ rend,
                                                  const int* __restrict__ csr,
                                                  const float* __restrict__ bias, const float* __restrict__ Ws,
                                                  float* __restrict__ hout, float* __restrict__ hss, int n)
{
    int nblk = gridDim.x;                       // multiple of 8
    int bid  = blockIdx.x;
    int b    = (bid & 7) * (nblk >> 3) + (bid >> 3);   // XCD chunk swizzle
    int half = threadIdx.x >> 5;
    int lane = threadIdx.x & 31;
    int node = (b << 3) + half;
    if (node >= n) return;
    const float4* Xf = XWs + lane;              // row r at Xf[r*32]

    float4 A = make_float4(0.f, 0.f, 0.f, 0.f), B = A, C = A, D = A;
    int p0 = rbeg[node], p1 = rend[node];
    int p = p0;
    for (; p + 8 <= p1; p += 8) {
        int s0 = csr[p], s1 = csr[p + 1], s2 = csr[p + 2], s3 = csr[p + 3];
        int s4 = csr[p + 4], s5 = csr[p + 5], s6 = csr[p + 6], s7 = csr[p + 7];
        float4 v0 = Xf[(size_t)s0 << 5], v1 = Xf[(size_t)s1 << 5];
        float4 v2 = Xf[(size_t)s2 << 5], v3 = Xf[(size_t)s3 << 5];
        float4 v4 = Xf[(size_t)s4 << 5], v5 = Xf[(size_t)s5 << 5];
        float4 v6 = Xf[(size_t)s6 << 5], v7 = Xf[(size_t)s7 << 5];
        A = f4add(A, v0); B = f4add(B, v1); C = f4add(C, v2); D = f4add(D, v3);
        A = f4add(A, v4); B = f4add(B, v5); C = f4add(C, v6); D = f4add(D, v7);
    }
    for (; p + 4 <= p1; p += 4) {
        int s0 = csr[p], s1 = csr[p + 1], s2 = csr[p + 2], s3 = csr[p + 3];
        float4 v0 = Xf[(size_t)s0 << 5], v1 = Xf[(size_t)s1 << 5];
        float4 v2 = Xf[(size_t)s2 << 5], v3 = Xf[(size_t)s3 << 5];
        A = f4add(A, v0); B = f4add(B, v1); C = f4add(C, v2); D = f4add(D, v3);
    }
    for (; p < p1; ++p) {
        int s = csr[p];
        A = f4add(A, Xf[(size_t)s << 5]);
    }
    float4 acc = f4add(f4add(A, B), f4add(C, D));
    acc = f4add(acc, Xf[(size_t)node << 5]);    // self term (prescaled)

    float dd = 1.0f / sqrtf((float)(p1 - p0) + 1.0f);
    float4 bb = *(const float4*)(bias + (lane << 2));
    acc.x = fmaxf(fmaf(acc.x, dd, bb.x), 0.f);
    acc.y = fmaxf(fmaf(acc.y, dd, bb.y), 0.f);
    acc.z = fmaxf(fmaf(acc.z, dd, bb.z), 0.f);
    acc.w = fmaxf(fmaf(acc.w, dd, bb.w), 0.f);
    *(float4*)(hout + ((size_t)node << 7) + (lane << 2)) = acc;

    float4 wsv = *(const float4*)(Ws + (lane << 2));
    float pq = acc.x * wsv.x + acc.y * wsv.y + acc.z * wsv.z + acc.w * wsv.w;
#pragma unroll
    for (int off = 16; off > 0; off >>= 1) pq += __shfl_down(pq, off, 32);
    if (lane == 0) hss[node] = dd * pq;         // prescaled score
}

// ---------------- fused score + per-graph top-k (+ nmap, + tanh(score)) -----------------
template <int NNE, int KK, bool MARK>
__global__ void sctopk_k(const int* __restrict__ rbeg, const int* __restrict__ rend,
                         const int* __restrict__ csr, const float* __restrict__ hss,
                         const float* __restrict__ bsp,
                         int* __restrict__ perm, float* __restrict__ tsel,
                         int* __restrict__ nmap)
{
    __shared__ unsigned long long keys[NNE];
    int t = threadIdx.x, g = blockIdx.x;
    int node = g * NNE + t;
    int p0 = rbeg[node], p1 = rend[node];
    float a = 0.f, b = 0.f, c = 0.f, e = 0.f;
    int p = p0;
    for (; p + 8 <= p1; p += 8) {
        int s0 = csr[p], s1 = csr[p + 1], s2 = csr[p + 2], s3 = csr[p + 3];
        int s4 = csr[p + 4], s5 = csr[p + 5], s6 = csr[p + 6], s7 = csr[p + 7];
        a += hss[s0]; b += hss[s1]; c += hss[s2]; e += hss[s3];
        a += hss[s4]; b += hss[s5]; c += hss[s6]; e += hss[s7];
    }
    for (; p + 4 <= p1; p += 4) {
        int s0 = csr[p], s1 = csr[p + 1], s2 = csr[p + 2], s3 = csr[p + 3];
        a += hss[s0]; b += hss[s1]; c += hss[s2]; e += hss[s3];
    }
    for (; p < p1; ++p) a += hss[csr[p]];
    float dd = 1.0f / sqrtf((float)(p1 - p0) + 1.0f);
    float s = fmaf((a + b) + (c + e) + hss[node], dd, bsp[0]);

    unsigned u = __float_as_uint(s);
    u = (u & 0x80000000u) ? ~u : (u | 0x80000000u);           // monotone map
    keys[t] = (((unsigned long long)u) << 32) | (unsigned)(NNE - 1 - t);
    __syncthreads();
    for (int k = 2; k <= NNE; k <<= 1) {
        for (int j = k >> 1; j > 0; j >>= 1) {
            int ixj = t ^ j;
            if (ixj > t) {
                unsigned long long ka = keys[t], kb = keys[ixj];
                bool up = ((t & k) == 0);
                if ((ka > kb) == up) { keys[t] = kb; keys[ixj] = ka; }
            }
            __syncthreads();
        }
    }
    unsigned long long key = keys[NNE - 1 - t];   // rank t
    int idx = NNE - 1 - (int)(key & 0xFFFFFFFFu);
    if (t < KK) {
        perm[g * KK + t] = g * NNE + idx;
        unsigned uu = (unsigned)(key >> 32);
        float sc = __uint_as_float((uu & 0x80000000u) ? (uu ^ 0x80000000u) : ~uu);
        tsel[g * KK + t] = tanhf(sc);
        if (MARK) nmap[g * NNE + idx] = g * KK + t;
    } else if (MARK) {
        nmap[g * NNE + idx] = -1;
    }
}

// ---------------- gather kept rows * tanh(score) ----------------
__global__ void gather_k(const float* __restrict__ h, const float* __restrict__ tsel,
                         const int* __restrict__ perm, float* __restrict__ xn)
{
    int nblk = gridDim.x;
    int bid  = blockIdx.x;
    int b    = (bid & 7) * (nblk >> 3) + (bid >> 3);   // XCD chunk swizzle
    int gid = b * 256 + threadIdx.x;
    int node = gid >> 5, f4 = (gid & 31) << 2;
    int o = perm[node];
    float tv = tsel[node];
    float4 v = *(const float4*)(h + ((size_t)o << 7) + f4);
    v.x *= tv; v.y *= tv; v.z *= tv; v.w *= tv;
    *(float4*)(xn + ((size_t)node << 7) + f4) = v;
}

// ---------------- readout partials: per-128-row chunk {max | sum} ----------------
__global__ __launch_bounds__(128) void readout_p_k(const float* __restrict__ xn, float* __restrict__ part)
{
    int b = blockIdx.x, t = threadIdx.x;
    const float* bp = xn + (size_t)b * (128 * 128);
    float mx = -INFINITY, sm = 0.f;
#pragma unroll 4
    for (int r = 0; r < 128; ++r) {
        float v = bp[r * 128 + t];
        mx = fmaxf(mx, v);
        sm += v;
    }
    part[b * 256 + t] = mx;
    part[b * 256 + 128 + t] = sm;
}

// ---------------- head: combine partials; z=x1+x2; relu(z@Wl1+bl1); @Wl2+bl2 ------------
__global__ __launch_bounds__(128) void mlp_k(const float* __restrict__ part1, const float* __restrict__ part2,
                                             const float* __restrict__ Wl1, const float* __restrict__ bl1,
                                             const float* __restrict__ Wl2, const float* __restrict__ bl2,
                                             float* __restrict__ out)
{
    __shared__ float z[256];
    __shared__ float red[128];
    int g = blockIdx.x, t = threadIdx.x;
    float mx1 = -INFINITY, sm1 = 0.f;
#pragma unroll
    for (int j = 0; j < 4; ++j) {
        mx1 = fmaxf(mx1, part1[(g * 4 + j) * 256 + t]);
        sm1 += part1[(g * 4 + j) * 256 + 128 + t];
    }
    float mx2 = -INFINITY, sm2 = 0.f;
#pragma unroll
    for (int j = 0; j < 2; ++j) {
        mx2 = fmaxf(mx2, part2[(g * 2 + j) * 256 + t]);
        sm2 += part2[(g * 2 + j) * 256 + 128 + t];
    }
    z[t]       = mx1 + mx2;
    z[t + 128] = sm1 * (1.f / 512.f) + sm2 * (1.f / 256.f);
    __syncthreads();
    float acc = bl1[t];
    for (int k = 0; k < 256; ++k) acc = fmaf(z[k], Wl1[k * 128 + t], acc);
    float zz = fmaxf(acc, 0.f);
    red[t] = zz * Wl2[t];
    __syncthreads();
    for (int off = 64; off > 0; off >>= 1) {
        if (t < off) red[t] += red[t + off];
        __syncthreads();
    }
    if (t == 0) out[g] = red[0] + bl2[0];
}

// ---------------- launch ----------------
extern "C" void kernel_launch(void* const* d_in, const int* in_sizes, int n_in,
                              void* d_out, int out_size, void* d_ws, size_t ws_size,
                              hipStream_t stream)
{
    const float* x   = (const float*)d_in[0];
    const int*   src = (const int*)d_in[1];
    const int*   dst = (const int*)d_in[2];
    const float* W1  = (const float*)d_in[3];
    const float* b1  = (const float*)d_in[4];
    const float* Ws1 = (const float*)d_in[5];
    const float* bs1 = (const float*)d_in[6];
    const float* W2  = (const float*)d_in[7];
    const float* b2  = (const float*)d_in[8];
    const float* Ws2 = (const float*)d_in[9];
    const float* bs2 = (const float*)d_in[10];
    const float* Wl1 = (const float*)d_in[11];
    const float* bl1 = (const float*)d_in[12];
    const float* Wl2 = (const float*)d_in[13];
    const float* bl2 = (const float*)d_in[14];
    float* out = (float*)d_out;
    char* ws = (char*)d_ws;

    // big regions (time-multiplexed)
    float* XW1 = (float*)(ws);                        // 32MB [0,32M)   (dinv-prescaled)
    float* h1  = (float*)(ws + ((size_t)32 << 20));   // 32MB [32M,64M)
    float* xn  = XW1;                                 // 16MB [0,16M)    (after agg1)
    float* XW2 = (float*)(ws + ((size_t)16 << 20));   // 16MB [16M,32M)  (after agg1)
    float* h2  = h1;                                  // 16MB [32M,48M)  (after gather1)
    float* xn2 = (float*)(ws + ((size_t)48 << 20));   // 8MB  [48M,56M)
    size_t SB = (size_t)64 << 20;
    auto alloc = [&](size_t bytes) { char* p = ws + SB; SB += (bytes + 255) & ~(size_t)255; return p; };
    int* csr1     = (int*)alloc((size_t)EE * 4);      // also reused as csr2 after sctopk1
    int* rbeg1    = (int*)alloc(NN1 * 4);
    int* rend1    = (int*)alloc(NN1 * 4);
    float* hss1   = (float*)alloc(NN1 * 4);
    int* nmap     = (int*)alloc(NN1 * 4);
    int* perm1    = (int*)alloc(M1 * 4);
    float* tsel1  = (float*)alloc(M1 * 4);
    int* rbeg2    = (int*)alloc(M1 * 4);
    int* rend2    = (int*)alloc(M1 * 4);
    float* hss2   = (float*)alloc(M1 * 4);
    int* perm2    = (int*)alloc(M2 * 4);
    float* tsel2  = (float*)alloc(M2 * 4);
    float* part1  = (float*)alloc(256 * 256 * 4);
    float* part2  = (float*)alloc(128 * 256 * 4);
    int* csr2     = csr1;
    (void)ws_size; (void)in_sizes; (void)n_in; (void)out_size;

    // ---- level 1 ----
    build_csr1_k<<<GG, 1024, 0, stream>>>(src, dst, rbeg1, rend1, csr1);
    gemm_f32_128<<<NN1 / 128, 256, 0, stream>>>(x, W1, rbeg1, rend1, XW1);
    agg_feat_k<<<NN1 / 8, 256, 0, stream>>>((const float4*)XW1, rbeg1, rend1, csr1, b1, Ws1, h1, hss1, NN1);
    sctopk_k<NPG, K1, true><<<GG, NPG, 0, stream>>>(rbeg1, rend1, csr1, hss1, bs1, perm1, tsel1, nmap);
    gather_k<<<(M1 * 32) / 256, 256, 0, stream>>>(h1, tsel1, perm1, xn);
    readout_p_k<<<M1 / 128, 128, 0, stream>>>(xn, part1);
    // ---- level 2 ----
    build_csr2_k<<<GG, 1024, 0, stream>>>(src, dst, nmap, rbeg2, rend2, csr2);
    gemm_f32_128<<<M1 / 128, 256, 0, stream>>>(xn, W2, rbeg2, rend2, XW2);
    agg_feat_k<<<M1 / 8, 256, 0, stream>>>((const float4*)XW2, rbeg2, rend2, csr2, b2, Ws2, h2, hss2, M1);
    sctopk_k<K1, K2, false><<<GG, K1, 0, stream>>>(rbeg2, rend2, csr2, hss2, bs2, perm2, tsel2, nullptr);
    gather_k<<<(M2 * 32) / 256, 256, 0, stream>>>(h2, tsel2, perm2, xn2);
    readout_p_k<<<M2 / 128, 128, 0, stream>>>(xn2, part2);
    // ---- head ----
    mlp_k<<<GG, 128, 0, stream>>>(part1, part2, Wl1, bl1, Wl2, bl2, out);
}